// Round 5
// baseline (267.869 us; speedup 1.0000x reference)
//
#include <hip/hip_runtime.h>
#include <hip/hip_bf16.h>
#include <math.h>

#define EPS 1e-6f
#define NSINK 1024
#define NSRC 4096
#define DIM 512
#define NH 8
#define HD 64
#define BATCH 2
// fold (d^-0.5 = 1/8) * log2(e) into q so sim exp is a single exp2
#define QSCALE 0.18033688011112042f

typedef unsigned short u16;
typedef __attribute__((ext_vector_type(8))) short short8;
typedef __attribute__((ext_vector_type(4))) float f32x4;

__device__ inline float fast_exp2(float x) {
#if __has_builtin(__builtin_amdgcn_exp2f)
    return __builtin_amdgcn_exp2f(x);
#else
    return exp2f(x);
#endif
}
__device__ inline float fast_rcp(float x) {
#if __has_builtin(__builtin_amdgcn_rcpf)
    return __builtin_amdgcn_rcpf(x);
#else
    return 1.0f / x;
#endif
}
__device__ inline u16 f2bf(float x) {
    union { float f; unsigned u; } v; v.f = x;
    unsigned r = v.u + 0x7fffu + ((v.u >> 16) & 1u);
    return (u16)(r >> 16);
}
__device__ inline float bf2f(u16 h) {
    union { unsigned u; float f; } v; v.u = ((unsigned)h) << 16;
    return v.f;
}
__device__ inline f32x4 mfma16(short8 a, short8 b, f32x4 c) {
    return __builtin_amdgcn_mfma_f32_16x16x32_bf16(a, b, c, 0, 0, 0);
}
// direct-from-global fragment loader (used by pass_a / pass_b)
__device__ inline short8 ldfrag(const u16* base, int stride, int lane) {
    return *(const short8*)(base + (size_t)(lane & 15) * stride + ((lane >> 4) << 3));
}

// async global->LDS, 16B per lane
__device__ inline void gld16(const u16* g, u16* l) {
    __builtin_amdgcn_global_load_lds(
        (const __attribute__((address_space(1))) unsigned*)g,
        (__attribute__((address_space(3))) unsigned*)l, 16, 0, 0);
}

// stage a [TM][64] bf16 tile (row-major, 128B rows) from gsrc (row-major, stride K)
// LDS linear dest; global source inverse-swizzled (c ^= m&7) -> swizzled reads conflict-free.
template<int TM>
__device__ inline void stage_tile(u16* lds, const u16* gsrc, int K, int t) {
    #pragma unroll
    for (int it = 0; it < TM / 32; ++it) {
        int m = it * 32 + (t >> 3);
        int c = (t & 7) ^ (m & 7);
        gld16(gsrc + (size_t)m * K + c * 8,
              lds + it * 2048 + (t >> 6) * 512);
    }
}
// swizzled fragment read
__device__ inline short8 rdfrag(const u16* tile, int fbase, int cbase, int lane) {
    int m = fbase + (lane & 15);
    int c = (cbase + (lane >> 4)) ^ (m & 7);
    return *(const short8*)(tile + (size_t)m * 64 + c * 8);
}

// ---------------- LayerNorm (row=512) -> split bf16 hi/lo ----------------
__global__ __launch_bounds__(256) void ln_split(const float* __restrict__ x,
    const float* __restrict__ g, const float* __restrict__ be,
    u16* __restrict__ yh, u16* __restrict__ yl)
{
    int row = blockIdx.x;
    int t = threadIdx.x;
    const float* xr = x + (size_t)row * DIM;
    float v0 = xr[t], v1 = xr[t + 256];
    float s = v0 + v1, sq = v0 * v0 + v1 * v1;
    #pragma unroll
    for (int off = 32; off > 0; off >>= 1) {
        s  += __shfl_down(s, off, 64);
        sq += __shfl_down(sq, off, 64);
    }
    __shared__ float rs[4], rq[4];
    int wave = t >> 6;
    if ((t & 63) == 0) { rs[wave] = s; rq[wave] = sq; }
    __syncthreads();
    s  = rs[0] + rs[1] + rs[2] + rs[3];
    sq = rq[0] + rq[1] + rq[2] + rq[3];
    float mu = s * (1.0f / DIM);
    float var = sq * (1.0f / DIM) - mu * mu;
    float a = var + EPS;
    float r = rsqrtf(a);
    r = r * (1.5f - 0.5f * a * r * r);
    size_t o = (size_t)row * DIM;
    float y0 = (v0 - mu) * r * g[t] + be[t];
    float y1 = (v1 - mu) * r * g[t + 256] + be[t + 256];
    u16 h0 = f2bf(y0), h1 = f2bf(y1);
    yh[o + t] = h0;        yl[o + t] = f2bf(y0 - bf2f(h0));
    yh[o + t + 256] = h1;  yl[o + t + 256] = f2bf(y1 - bf2f(h1));
}

// ---------------- weight transpose + split: W[K][N] -> T{h,l}[N][K] ----------------
__global__ __launch_bounds__(256) void wt_split(const float* __restrict__ W, int K, int N,
    u16* __restrict__ Th, u16* __restrict__ Tl)
{
    int n = blockIdx.x;
    for (int k = threadIdx.x; k < K; k += 256) {
        float w = W[(size_t)k * N + n];
        u16 h = f2bf(w);
        Th[(size_t)n * K + k] = h;
        Tl[(size_t)n * K + k] = f2bf(w - bf2f(h));
    }
}

// ---------------- LDS-staged MFMA GEMM: C = A @ BT^T + bias ----------------
template<int MODE, int TM, int TN>
__global__ __launch_bounds__(256) void gemm_lds(
    const u16* __restrict__ Ah, const u16* __restrict__ Al,
    const u16* __restrict__ BTh, const u16* __restrict__ BTl,
    const float* __restrict__ bias, int K,
    float* __restrict__ cf, u16* __restrict__ o1,
    u16* __restrict__ o2, u16* __restrict__ o3)
{
    constexpr int NSPLIT = (MODE == 1) ? 1 : 2;
    constexpr int FM = TM / 32, FN = TN / 32;
    __shared__ u16 As[NSPLIT][TM * 64];
    __shared__ u16 Bs[NSPLIT][TN * 64];
    int t = threadIdx.x;
    int wave = t >> 6, lane = t & 63;
    int wr = wave >> 1, wc = wave & 1;
    int m0 = blockIdx.y * TM, n0 = blockIdx.x * TN;
    bool three = (MODE == 0) || (MODE == 2 && n0 >= DIM);

    f32x4 acc[FM][FN] = {};
    for (int k0 = 0; k0 < K; k0 += 64) {
        stage_tile<TM>(&As[0][0], Ah + (size_t)m0 * K + k0, K, t);
        stage_tile<TN>(&Bs[0][0], BTh + (size_t)n0 * K + k0, K, t);
        if constexpr (MODE != 1) {
            if (three) {
                stage_tile<TM>(&As[1][0], Al + (size_t)m0 * K + k0, K, t);
                stage_tile<TN>(&Bs[1][0], BTl + (size_t)n0 * K + k0, K, t);
            }
        }
        __syncthreads();
        #pragma unroll
        for (int kk = 0; kk < 2; ++kk) {
            short8 afh[FM], bfh[FN];
            #pragma unroll
            for (int f = 0; f < FM; ++f)
                afh[f] = rdfrag(&As[0][0], wr * (TM / 2) + f * 16, kk * 4, lane);
            #pragma unroll
            for (int f = 0; f < FN; ++f)
                bfh[f] = rdfrag(&Bs[0][0], wc * (TN / 2) + f * 16, kk * 4, lane);
            if constexpr (MODE != 1) {
                if (three) {
                    short8 afl[FM], bfl[FN];
                    #pragma unroll
                    for (int f = 0; f < FM; ++f)
                        afl[f] = rdfrag(&As[1][0], wr * (TM / 2) + f * 16, kk * 4, lane);
                    #pragma unroll
                    for (int f = 0; f < FN; ++f)
                        bfl[f] = rdfrag(&Bs[1][0], wc * (TN / 2) + f * 16, kk * 4, lane);
                    #pragma unroll
                    for (int i = 0; i < FM; ++i)
                        #pragma unroll
                        for (int j = 0; j < FN; ++j) {
                            acc[i][j] = mfma16(afl[i], bfh[j], acc[i][j]);
                            acc[i][j] = mfma16(afh[i], bfl[j], acc[i][j]);
                            acc[i][j] = mfma16(afh[i], bfh[j], acc[i][j]);
                        }
                } else {
                    #pragma unroll
                    for (int i = 0; i < FM; ++i)
                        #pragma unroll
                        for (int j = 0; j < FN; ++j)
                            acc[i][j] = mfma16(afh[i], bfh[j], acc[i][j]);
                }
            } else {
                #pragma unroll
                for (int i = 0; i < FM; ++i)
                    #pragma unroll
                    for (int j = 0; j < FN; ++j)
                        acc[i][j] = mfma16(afh[i], bfh[j], acc[i][j]);
            }
        }
        __syncthreads();
    }

    #pragma unroll
    for (int i = 0; i < FM; ++i)
        #pragma unroll
        for (int j = 0; j < FN; ++j)
            #pragma unroll
            for (int r = 0; r < 4; ++r) {
                int m = m0 + wr * (TM / 2) + i * 16 + (lane >> 4) * 4 + r;
                int n = n0 + wc * (TN / 2) + j * 16 + (lane & 15);
                float v = acc[i][j][r] + bias[n];
                if (MODE == 0) {
                    cf[(size_t)m * DIM + n] = v;
                } else if (MODE == 1) {
                    int b = m >> 10, ii = m & 1023;
                    int h = n >> 6, d = n & 63;
                    o1[((size_t)(b * NH + h) * NSINK + ii) * HD + d] = f2bf(v * QSCALE);
                } else {
                    int b = m >> 12, jj = m & 4095;
                    if (n < DIM) {
                        int h = n >> 6, d = n & 63;
                        o1[((size_t)(b * NH + h) * NSRC + jj) * HD + d] = f2bf(v);
                    } else {
                        int nn = n - DIM;
                        int h = nn >> 6, d = nn & 63;
                        size_t off = ((size_t)(b * NH + h) * HD + d) * NSRC + jj;
                        u16 hh = f2bf(v);
                        o2[off] = hh;
                        o3[off] = f2bf(v - bf2f(hh));
                    }
                }
            }
}

// ---------------- vsum[bh*64+d] = sum_j v ----------------
__global__ __launch_bounds__(256) void vsum_k(const u16* __restrict__ vTh,
    const u16* __restrict__ vTl, float* __restrict__ vs)
{
    int row = blockIdx.x;
    const u16* ph = vTh + (size_t)row * NSRC;
    const u16* pl = vTl + (size_t)row * NSRC;
    float s = 0.f;
    for (int j = threadIdx.x; j < NSRC; j += 256) s += bf2f(ph[j]) + bf2f(pl[j]);
    #pragma unroll
    for (int off = 32; off > 0; off >>= 1) s += __shfl_down(s, off, 64);
    __shared__ float r4[4];
    if ((threadIdx.x & 63) == 0) r4[threadIdx.x >> 6] = s;
    __syncthreads();
    if (threadIdx.x == 0) vs[row] = r4[0] + r4[1] + r4[2] + r4[3];
}

// ---------------- pass A: colsum_part[ic][bh][j] = sum_{i in chunk} exp2(q.k) ----------------
// grid (16 j-tiles, 16 bh, 4 i-chunks), 256 thr
__global__ __launch_bounds__(256, 4) void pass_a(const u16* __restrict__ q,
    const u16* __restrict__ k, float* __restrict__ part)
{
    int bh = blockIdx.y, ic = blockIdx.z;
    int wave = threadIdx.x >> 6, lane = threadIdx.x & 63;
    int j0 = blockIdx.x * 256 + wave * 64;
    const u16* qb = q + (size_t)bh * NSINK * HD;
    const u16* kb = k + (size_t)bh * NSRC * HD;
    short8 kf[4][2];
    #pragma unroll
    for (int jf = 0; jf < 4; ++jf)
        #pragma unroll
        for (int kc = 0; kc < 2; ++kc)
            kf[jf][kc] = ldfrag(kb + (size_t)(j0 + jf * 16) * HD + kc * 32, HD, lane);
    float csum[4] = {};
    for (int ii = 0; ii < 4; ++ii) {
        int ibase = ic * 256 + ii * 64;
        #pragma unroll
        for (int f = 0; f < 4; ++f) {
            short8 q0 = ldfrag(qb + (size_t)(ibase + f * 16) * HD, HD, lane);
            short8 q1 = ldfrag(qb + (size_t)(ibase + f * 16) * HD + 32, HD, lane);
            f32x4 s[4] = {};
            #pragma unroll
            for (int jf = 0; jf < 4; ++jf) s[jf] = mfma16(q0, kf[jf][0], s[jf]);
            #pragma unroll
            for (int jf = 0; jf < 4; ++jf) s[jf] = mfma16(q1, kf[jf][1], s[jf]);
            #pragma unroll
            for (int jf = 0; jf < 4; ++jf)
                csum[jf] += fast_exp2(s[jf][0]) + fast_exp2(s[jf][1])
                          + fast_exp2(s[jf][2]) + fast_exp2(s[jf][3]);
        }
    }
    #pragma unroll
    for (int jf = 0; jf < 4; ++jf) {
        csum[jf] += __shfl_xor(csum[jf], 16, 64);
        csum[jf] += __shfl_xor(csum[jf], 32, 64);
    }
    if (lane < 16)
        #pragma unroll
        for (int jf = 0; jf < 4; ++jf)
            part[((size_t)ic * BATCH * NH + bh) * NSRC + j0 + jf * 16 + lane] = csum[jf];
}

// colsum[x] = sum_ic part[ic][x]
__global__ __launch_bounds__(256) void csum_red(const float* __restrict__ part,
    float* __restrict__ colsum)
{
    int x = blockIdx.x * 256 + threadIdx.x;
    const int S = BATCH * NH * NSRC;
    colsum[x] = part[x] + part[x + S] + part[x + 2 * S] + part[x + 3 * S];
}

// ---------------- pass B: pv[i][hd], rowsum[i] per j-quarter ----------------
// grid (16 i-tiles, 4 j-splits, 16 bh)
__global__ __launch_bounds__(256, 4) void pass_b(const u16* __restrict__ q,
    const u16* __restrict__ k, const u16* __restrict__ vTh, const u16* __restrict__ vTl,
    const float* __restrict__ colsum, float* __restrict__ pv, float* __restrict__ rs)
{
    int bh = blockIdx.z, i0 = blockIdx.x * 64, split = blockIdx.y;
    int wave = threadIdx.x >> 6, lane = threadIdx.x & 63;
    const u16* qb = q + (size_t)bh * NSINK * HD;
    const u16* kb = k + (size_t)bh * NSRC * HD;
    const u16* vh = vTh + (size_t)bh * HD * NSRC;
    const u16* vl = vTl + (size_t)bh * HD * NSRC;
    __shared__ alignas(16) u16 pbuf[4][64 * 72];
    __shared__ float rsums[4][64];
    short8 qf[4][2];
    #pragma unroll
    for (int f = 0; f < 4; ++f)
        #pragma unroll
        for (int kc = 0; kc < 2; ++kc)
            qf[f][kc] = ldfrag(qb + (size_t)(i0 + f * 16) * HD + kc * 32, HD, lane);
    f32x4 o[4][4] = {};
    float rsum[4][4] = {};
    for (int jt = 0; jt < 4; ++jt) {
        int j0 = split * (NSRC / 4) + jt * 256 + wave * 64;
        short8 kf[4][2];
        #pragma unroll
        for (int jf = 0; jf < 4; ++jf)
            #pragma unroll
            for (int kc = 0; kc < 2; ++kc)
                kf[jf][kc] = ldfrag(kb + (size_t)(j0 + jf * 16) * HD + kc * 32, HD, lane);
        float inv[4];
        #pragma unroll
        for (int jf = 0; jf < 4; ++jf)
            inv[jf] = fast_rcp(colsum[(size_t)bh * NSRC + j0 + jf * 16 + (lane & 15)]);
        #pragma unroll
        for (int i = 0; i < 4; ++i) {
            f32x4 s[4] = {};
            #pragma unroll
            for (int kc = 0; kc < 2; ++kc)
                #pragma unroll
                for (int jf = 0; jf < 4; ++jf)
                    s[jf] = mfma16(qf[i][kc], kf[jf][kc], s[jf]);
            #pragma unroll
            for (int jf = 0; jf < 4; ++jf) {
                float p0 = fast_exp2(s[jf][0]) * inv[jf];
                float p1 = fast_exp2(s[jf][1]) * inv[jf];
                float p2 = fast_exp2(s[jf][2]) * inv[jf];
                float p3 = fast_exp2(s[jf][3]) * inv[jf];
                rsum[i][0] += p0; rsum[i][1] += p1; rsum[i][2] += p2; rsum[i][3] += p3;
                u16* dst = &pbuf[wave][(size_t)(i * 16 + (lane >> 4) * 4) * 72 + jf * 16 + (lane & 15)];
                dst[0]      = f2bf(p0);
                dst[72]     = f2bf(p1);
                dst[2 * 72] = f2bf(p2);
                dst[3 * 72] = f2bf(p3);
            }
        }
        __syncthreads();
        #pragma unroll
        for (int jc = 0; jc < 2; ++jc) {
            short8 pa[4];
            #pragma unroll
            for (int f = 0; f < 4; ++f)
                pa[f] = *(const short8*)&pbuf[wave][(size_t)(f * 16 + (lane & 15)) * 72 + jc * 32 + (lane >> 4) * 8];
            #pragma unroll
            for (int df = 0; df < 4; ++df) {
                short8 bhf = ldfrag(vh + (size_t)(df * 16) * NSRC + j0 + jc * 32, NSRC, lane);
                short8 blf = ldfrag(vl + (size_t)(df * 16) * NSRC + j0 + jc * 32, NSRC, lane);
                #pragma unroll
                for (int i = 0; i < 4; ++i) {
                    o[i][df] = mfma16(pa[i], bhf, o[i][df]);
                    o[i][df] = mfma16(pa[i], blf, o[i][df]);
                }
            }
        }
        __syncthreads();
    }
    // rowsum reduce within wave
    #pragma unroll
    for (int i = 0; i < 4; ++i)
        #pragma unroll
        for (int r = 0; r < 4; ++r) {
            float v = rsum[i][r];
            v += __shfl_xor(v, 1, 64); v += __shfl_xor(v, 2, 64);
            v += __shfl_xor(v, 4, 64); v += __shfl_xor(v, 8, 64);
            if ((lane & 15) == 0) rsums[wave][i * 16 + (lane >> 4) * 4 + r] = v;
        }
    // cross-wave reduction of o (waves hold disjoint key chunks)
    float* redo = (float*)&pbuf[0][0];
    for (int w = 0; w < 4; ++w) {
        if (wave == w) {
            #pragma unroll
            for (int i = 0; i < 4; ++i)
                #pragma unroll
                for (int df = 0; df < 4; ++df)
                    #pragma unroll
                    for (int r = 0; r < 4; ++r) {
                        int row = i * 16 + (lane >> 4) * 4 + r;
                        int col = df * 16 + (lane & 15);
                        if (w == 0) redo[row * 68 + col] = o[i][df][r];
                        else        redo[row * 68 + col] += o[i][df][r];
                    }
        }
        __syncthreads();
    }
    if (threadIdx.x < 64) {
        float v = rsums[0][threadIdx.x] + rsums[1][threadIdx.x]
                + rsums[2][threadIdx.x] + rsums[3][threadIdx.x];
        rs[((size_t)split * (BATCH * NH) + bh) * NSINK + i0 + threadIdx.x] = v;
    }
    int b = bh >> 3, h = bh & 7;
    float* pvp = pv + (size_t)split * BATCH * NSINK * DIM;
    {
        int row = threadIdx.x >> 2, cb = (threadIdx.x & 3) * 16;
        float* dst = &pvp[((size_t)(b * NSINK + i0 + row)) * DIM + h * HD + cb];
        #pragma unroll
        for (int jj = 0; jj < 16; ++jj) dst[jj] = redo[row * 68 + cb + jj];
    }
}

// ---------------- finalize: a = (sum pv + eps*vsum)/(sum rs + Neps) -> split bf16 ----------------
__global__ __launch_bounds__(256) void finalize_pv(const float* __restrict__ pv,
    const float* __restrict__ rs, const float* __restrict__ vs,
    u16* __restrict__ ah, u16* __restrict__ al)
{
    const int M = BATCH * NSINK * DIM;
    const int R = BATCH * NH * NSINK;
    int idx = blockIdx.x * 256 + threadIdx.x;
    int m = idx >> 9, n = idx & 511;
    int b = m >> 10, i = m & 1023, h = n >> 6, d = n & 63;
    int bh = b * NH + h;
    float val = pv[idx] + pv[idx + M] + pv[idx + 2 * M] + pv[idx + 3 * M]
              + EPS * vs[bh * HD + d];
    float rsv = rs[bh * NSINK + i] + rs[R + bh * NSINK + i]
              + rs[2 * R + bh * NSINK + i] + rs[3 * R + bh * NSINK + i]
              + (float)NSRC * EPS;
    val /= rsv;
    u16 hh = f2bf(val);
    ah[idx] = hh;
    al[idx] = f2bf(val - bf2f(hh));
}

extern "C" void kernel_launch(void* const* d_in, const int* in_sizes, int n_in,
                              void* d_out, int out_size, void* d_ws, size_t ws_size,
                              hipStream_t stream) {
    (void)in_sizes; (void)n_in; (void)out_size;
    const float* sink    = (const float*)d_in[0];
    const float* source  = (const float*)d_in[1];
    const float* gamma_s = (const float*)d_in[2];
    const float* beta_s  = (const float*)d_in[3];
    const float* gamma_c = (const float*)d_in[4];
    const float* beta_c  = (const float*)d_in[5];
    const float* Wq      = (const float*)d_in[6];
    const float* bq      = (const float*)d_in[7];
    const float* Wkv     = (const float*)d_in[8];
    const float* bkv     = (const float*)d_in[9];
    const float* Wo      = (const float*)d_in[10];
    const float* bo      = (const float*)d_in[11];
    float* out = (float*)d_out;

    char* p = (char*)d_ws;
    auto carve = [&](size_t bytes) { char* r = p; p += (bytes + 255) & ~(size_t)255; return r; };
    u16* sh    = (u16*)carve(2048ull * 512 * 2);
    u16* sl    = (u16*)carve(2048ull * 512 * 2);
    u16* ch    = (u16*)carve(8192ull * 512 * 2);   // 8 MB
    u16* cl    = (u16*)carve(8192ull * 512 * 2);   // 8 MB (contiguous after ch)
    u16* wqTh  = (u16*)carve(512ull * 512 * 2);
    u16* wqTl  = (u16*)carve(512ull * 512 * 2);
    u16* wkvTh = (u16*)carve(1024ull * 512 * 2);
    u16* wkvTl = (u16*)carve(1024ull * 512 * 2);
    u16* woTh  = (u16*)carve(512ull * 512 * 2);
    u16* woTl  = (u16*)carve(512ull * 512 * 2);
    u16* qb    = (u16*)carve(16ull * 1024 * 64 * 2);
    u16* kb    = (u16*)carve(16ull * 4096 * 64 * 2);
    u16* vTh   = (u16*)carve(16ull * 64 * 4096 * 2);
    u16* vTl   = (u16*)carve(16ull * 64 * 4096 * 2);
    float* colsum  = (float*)carve(16ull * 4096 * 4);
    float* cs_part = (float*)carve(4ull * 16 * 4096 * 4);
    float* vs      = (float*)carve(1024ull * 4);
    float* rs      = (float*)carve(4ull * 16 * 1024 * 4);
    if ((size_t)(p - (char*)d_ws) > ws_size) return;
    // lifetime aliases: pv (16 MB) over ch+cl (dead after KV gemm);
    // ah/al over sh/sl (dead after Q gemm)
    float* pv = (float*)ch;
    u16*   ah = sh;
    u16*   al = sl;

    ln_split<<<BATCH * NSINK, 256, 0, stream>>>(sink, gamma_s, beta_s, sh, sl);
    ln_split<<<BATCH * NSRC,  256, 0, stream>>>(source, gamma_c, beta_c, ch, cl);
    wt_split<<<512,  256, 0, stream>>>(Wq, 512, 512, wqTh, wqTl);
    wt_split<<<1024, 256, 0, stream>>>(Wkv, 512, 1024, wkvTh, wkvTl);
    wt_split<<<512,  256, 0, stream>>>(Wo, 512, 512, woTh, woTl);

    // Q: 1-term, 64x64 tiles
    gemm_lds<1, 64, 64><<<dim3(DIM / 64, BATCH * NSINK / 64), 256, 0, stream>>>(
        sh, nullptr, wqTh, nullptr, bq, 512, nullptr, qb, nullptr, nullptr);
    // KV: mixed 1/3-term, 128x128 tiles
    gemm_lds<2, 128, 128><<<dim3(2 * DIM / 128, BATCH * NSRC / 128), 256, 0, stream>>>(
        ch, cl, wkvTh, wkvTl, bkv, 512, nullptr, kb, vTh, vTl);

    vsum_k<<<1024, 256, 0, stream>>>(vTh, vTl, vs);
    pass_a<<<dim3(16, 16, 4), 256, 0, stream>>>(qb, kb, cs_part);
    csum_red<<<BATCH * NH * NSRC / 256, 256, 0, stream>>>(cs_part, colsum);
    pass_b<<<dim3(16, 4, 16), 256, 0, stream>>>(qb, kb, vTh, vTl, colsum, pv, rs);
    finalize_pv<<<4096, 256, 0, stream>>>(pv, rs, vs, ah, al);

    // out: 3-term, 64x64 tiles
    gemm_lds<0, 64, 64><<<dim3(DIM / 64, BATCH * NSINK / 64), 256, 0, stream>>>(
        ah, al, woTh, woTl, bo, 512, out, nullptr, nullptr, nullptr);
}

// Round 6
// 196.795 us; speedup vs baseline: 1.3612x; 1.3612x over previous
//
#include <hip/hip_runtime.h>
#include <hip/hip_bf16.h>
#include <math.h>

#define EPS 1e-6f
#define NSINK 1024
#define NSRC 4096
#define DIM 512
#define NH 8
#define HD 64
#define BATCH 2
// fold (d^-0.5 = 1/8) * log2(e) into q so sim exp is a single exp2
#define QSCALE 0.18033688011112042f

typedef unsigned short u16;
typedef __attribute__((ext_vector_type(8))) short short8;
typedef __attribute__((ext_vector_type(4))) float f32x4;

__device__ inline float fast_exp2(float x) {
#if __has_builtin(__builtin_amdgcn_exp2f)
    return __builtin_amdgcn_exp2f(x);
#else
    return exp2f(x);
#endif
}
__device__ inline float fast_rcp(float x) {
#if __has_builtin(__builtin_amdgcn_rcpf)
    return __builtin_amdgcn_rcpf(x);
#else
    return 1.0f / x;
#endif
}
__device__ inline u16 f2bf(float x) {
    union { float f; unsigned u; } v; v.f = x;
    unsigned r = v.u + 0x7fffu + ((v.u >> 16) & 1u);
    return (u16)(r >> 16);
}
__device__ inline float bf2f(u16 h) {
    union { unsigned u; float f; } v; v.u = ((unsigned)h) << 16;
    return v.f;
}
__device__ inline f32x4 mfma16(short8 a, short8 b, f32x4 c) {
    return __builtin_amdgcn_mfma_f32_16x16x32_bf16(a, b, c, 0, 0, 0);
}
// direct-from-global fragment loader
__device__ inline short8 ldfrag(const u16* base, int stride, int lane) {
    return *(const short8*)(base + (size_t)(lane & 15) * stride + ((lane >> 4) << 3));
}

// async global->LDS, 16B per lane
__device__ inline void gld16(const u16* g, u16* l) {
    __builtin_amdgcn_global_load_lds(
        (const __attribute__((address_space(1))) unsigned*)g,
        (__attribute__((address_space(3))) unsigned*)l, 16, 0, 0);
}

// stage a [TM][64] bf16 tile from gsrc (row-major, stride K);
// LDS linear dest; global source inverse-swizzled (c ^= m&7).
template<int TM>
__device__ inline void stage_tile(u16* lds, const u16* gsrc, int K, int t) {
    #pragma unroll
    for (int it = 0; it < TM / 32; ++it) {
        int m = it * 32 + (t >> 3);
        int c = (t & 7) ^ (m & 7);
        gld16(gsrc + (size_t)m * K + c * 8,
              lds + it * 2048 + (t >> 6) * 512);
    }
}
// swizzled fragment read
__device__ inline short8 rdfrag(const u16* tile, int fbase, int cbase, int lane) {
    int m = fbase + (lane & 15);
    int c = (cbase + (lane >> 4)) ^ (m & 7);
    return *(const short8*)(tile + (size_t)m * 64 + c * 8);
}

// ---------------- LayerNorm (row=512) -> split bf16 hi/lo ----------------
__global__ __launch_bounds__(256) void ln_split(const float* __restrict__ x,
    const float* __restrict__ g, const float* __restrict__ be,
    u16* __restrict__ yh, u16* __restrict__ yl)
{
    int row = blockIdx.x;
    int t = threadIdx.x;
    const float* xr = x + (size_t)row * DIM;
    float v0 = xr[t], v1 = xr[t + 256];
    float s = v0 + v1, sq = v0 * v0 + v1 * v1;
    #pragma unroll
    for (int off = 32; off > 0; off >>= 1) {
        s  += __shfl_down(s, off, 64);
        sq += __shfl_down(sq, off, 64);
    }
    __shared__ float rs[4], rq[4];
    int wave = t >> 6;
    if ((t & 63) == 0) { rs[wave] = s; rq[wave] = sq; }
    __syncthreads();
    s  = rs[0] + rs[1] + rs[2] + rs[3];
    sq = rq[0] + rq[1] + rq[2] + rq[3];
    float mu = s * (1.0f / DIM);
    float var = sq * (1.0f / DIM) - mu * mu;
    float a = var + EPS;
    float r = rsqrtf(a);
    r = r * (1.5f - 0.5f * a * r * r);
    size_t o = (size_t)row * DIM;
    float y0 = (v0 - mu) * r * g[t] + be[t];
    float y1 = (v1 - mu) * r * g[t + 256] + be[t + 256];
    u16 h0 = f2bf(y0), h1 = f2bf(y1);
    yh[o + t] = h0;        yl[o + t] = f2bf(y0 - bf2f(h0));
    yh[o + t + 256] = h1;  yl[o + t + 256] = f2bf(y1 - bf2f(h1));
}

// ---------------- weight transpose + split: W[K][N] -> T{h,l}[N][K] ----------------
__global__ __launch_bounds__(256) void wt_split(const float* __restrict__ W, int K, int N,
    u16* __restrict__ Th, u16* __restrict__ Tl)
{
    int n = blockIdx.x;
    for (int k = threadIdx.x; k < K; k += 256) {
        float w = W[(size_t)k * N + n];
        u16 h = f2bf(w);
        Th[(size_t)n * K + k] = h;
        Tl[(size_t)n * K + k] = f2bf(w - bf2f(h));
    }
}

// ---------------- LDS-staged MFMA GEMM: C = A @ BT^T + bias ----------------
template<int MODE, int TM, int TN>
__global__ __launch_bounds__(256) void gemm_lds(
    const u16* __restrict__ Ah, const u16* __restrict__ Al,
    const u16* __restrict__ BTh, const u16* __restrict__ BTl,
    const float* __restrict__ bias, int K,
    float* __restrict__ cf, u16* __restrict__ o1,
    u16* __restrict__ o2, u16* __restrict__ o3)
{
    constexpr int NSPLIT = (MODE == 1) ? 1 : 2;
    constexpr int FM = TM / 32, FN = TN / 32;
    __shared__ u16 As[NSPLIT][TM * 64];
    __shared__ u16 Bs[NSPLIT][TN * 64];
    int t = threadIdx.x;
    int wave = t >> 6, lane = t & 63;
    int wr = wave >> 1, wc = wave & 1;
    int m0 = blockIdx.y * TM, n0 = blockIdx.x * TN;
    bool three = (MODE == 0) || (MODE == 2 && n0 >= DIM);

    f32x4 acc[FM][FN] = {};
    for (int k0 = 0; k0 < K; k0 += 64) {
        stage_tile<TM>(&As[0][0], Ah + (size_t)m0 * K + k0, K, t);
        stage_tile<TN>(&Bs[0][0], BTh + (size_t)n0 * K + k0, K, t);
        if constexpr (MODE != 1) {
            if (three) {
                stage_tile<TM>(&As[1][0], Al + (size_t)m0 * K + k0, K, t);
                stage_tile<TN>(&Bs[1][0], BTl + (size_t)n0 * K + k0, K, t);
            }
        }
        __syncthreads();
        #pragma unroll
        for (int kk = 0; kk < 2; ++kk) {
            short8 afh[FM], bfh[FN];
            #pragma unroll
            for (int f = 0; f < FM; ++f)
                afh[f] = rdfrag(&As[0][0], wr * (TM / 2) + f * 16, kk * 4, lane);
            #pragma unroll
            for (int f = 0; f < FN; ++f)
                bfh[f] = rdfrag(&Bs[0][0], wc * (TN / 2) + f * 16, kk * 4, lane);
            if constexpr (MODE != 1) {
                if (three) {
                    short8 afl[FM], bfl[FN];
                    #pragma unroll
                    for (int f = 0; f < FM; ++f)
                        afl[f] = rdfrag(&As[1][0], wr * (TM / 2) + f * 16, kk * 4, lane);
                    #pragma unroll
                    for (int f = 0; f < FN; ++f)
                        bfl[f] = rdfrag(&Bs[1][0], wc * (TN / 2) + f * 16, kk * 4, lane);
                    #pragma unroll
                    for (int i = 0; i < FM; ++i)
                        #pragma unroll
                        for (int j = 0; j < FN; ++j) {
                            acc[i][j] = mfma16(afl[i], bfh[j], acc[i][j]);
                            acc[i][j] = mfma16(afh[i], bfl[j], acc[i][j]);
                            acc[i][j] = mfma16(afh[i], bfh[j], acc[i][j]);
                        }
                } else {
                    #pragma unroll
                    for (int i = 0; i < FM; ++i)
                        #pragma unroll
                        for (int j = 0; j < FN; ++j)
                            acc[i][j] = mfma16(afh[i], bfh[j], acc[i][j]);
                }
            } else {
                #pragma unroll
                for (int i = 0; i < FM; ++i)
                    #pragma unroll
                    for (int j = 0; j < FN; ++j)
                        acc[i][j] = mfma16(afh[i], bfh[j], acc[i][j]);
            }
        }
        __syncthreads();
    }

    #pragma unroll
    for (int i = 0; i < FM; ++i)
        #pragma unroll
        for (int j = 0; j < FN; ++j)
            #pragma unroll
            for (int r = 0; r < 4; ++r) {
                int m = m0 + wr * (TM / 2) + i * 16 + (lane >> 4) * 4 + r;
                int n = n0 + wc * (TN / 2) + j * 16 + (lane & 15);
                float v = acc[i][j][r] + bias[n];
                if (MODE == 0) {
                    cf[(size_t)m * DIM + n] = v;
                } else if (MODE == 1) {
                    int b = m >> 10, ii = m & 1023;
                    int h = n >> 6, d = n & 63;
                    o1[((size_t)(b * NH + h) * NSINK + ii) * HD + d] = f2bf(v * QSCALE);
                } else {
                    int b = m >> 12, jj = m & 4095;
                    if (n < DIM) {
                        int h = n >> 6, d = n & 63;
                        o1[((size_t)(b * NH + h) * NSRC + jj) * HD + d] = f2bf(v);
                    } else {
                        int nn = n - DIM;
                        int h = nn >> 6, d = nn & 63;
                        size_t off = ((size_t)(b * NH + h) * HD + d) * NSRC + jj;
                        u16 hh = f2bf(v);
                        o2[off] = hh;
                        o3[off] = f2bf(v - bf2f(hh));
                    }
                }
            }
}

// ---------------- vsum[bh*64+d] = sum_j v ----------------
__global__ __launch_bounds__(256) void vsum_k(const u16* __restrict__ vTh,
    const u16* __restrict__ vTl, float* __restrict__ vs)
{
    int row = blockIdx.x;
    const u16* ph = vTh + (size_t)row * NSRC;
    const u16* pl = vTl + (size_t)row * NSRC;
    float s = 0.f;
    for (int j = threadIdx.x; j < NSRC; j += 256) s += bf2f(ph[j]) + bf2f(pl[j]);
    #pragma unroll
    for (int off = 32; off > 0; off >>= 1) s += __shfl_down(s, off, 64);
    __shared__ float r4[4];
    if ((threadIdx.x & 63) == 0) r4[threadIdx.x >> 6] = s;
    __syncthreads();
    if (threadIdx.x == 0) vs[row] = r4[0] + r4[1] + r4[2] + r4[3];
}

// ---------------- pass A: colsum_part[ic][bh][j] = sum_{i chunk} exp2(q.k) ----------------
// 1-D grid 1024, XCD-affine decode: id%8 == bh%8
__global__ __launch_bounds__(256, 4) void pass_a(const u16* __restrict__ q,
    const u16* __restrict__ k, float* __restrict__ part)
{
    int id = blockIdx.x;
    int slot = id >> 3;
    int bh = (id & 7) + 8 * (slot >> 6);
    int rem = slot & 63;
    int ic = rem >> 4;
    int wave = threadIdx.x >> 6, lane = threadIdx.x & 63;
    int j0 = (rem & 15) * 256 + wave * 64;
    const u16* qb = q + (size_t)bh * NSINK * HD;
    const u16* kb = k + (size_t)bh * NSRC * HD;
    short8 kf[4][2];
    #pragma unroll
    for (int jf = 0; jf < 4; ++jf)
        #pragma unroll
        for (int kc = 0; kc < 2; ++kc)
            kf[jf][kc] = ldfrag(kb + (size_t)(j0 + jf * 16) * HD + kc * 32, HD, lane);
    float csum[4] = {};
    for (int ii = 0; ii < 4; ++ii) {
        int ibase = ic * 256 + ii * 64;
        #pragma unroll
        for (int f = 0; f < 4; ++f) {
            short8 q0 = ldfrag(qb + (size_t)(ibase + f * 16) * HD, HD, lane);
            short8 q1 = ldfrag(qb + (size_t)(ibase + f * 16) * HD + 32, HD, lane);
            f32x4 s[4] = {};
            #pragma unroll
            for (int jf = 0; jf < 4; ++jf) s[jf] = mfma16(q0, kf[jf][0], s[jf]);
            #pragma unroll
            for (int jf = 0; jf < 4; ++jf) s[jf] = mfma16(q1, kf[jf][1], s[jf]);
            #pragma unroll
            for (int jf = 0; jf < 4; ++jf)
                csum[jf] += fast_exp2(s[jf][0]) + fast_exp2(s[jf][1])
                          + fast_exp2(s[jf][2]) + fast_exp2(s[jf][3]);
        }
    }
    #pragma unroll
    for (int jf = 0; jf < 4; ++jf) {
        csum[jf] += __shfl_xor(csum[jf], 16, 64);
        csum[jf] += __shfl_xor(csum[jf], 32, 64);
    }
    if (lane < 16)
        #pragma unroll
        for (int jf = 0; jf < 4; ++jf)
            part[((size_t)ic * BATCH * NH + bh) * NSRC + j0 + jf * 16 + lane] = csum[jf];
}

// colsum[x] = sum_ic part[ic][x]
__global__ __launch_bounds__(256) void csum_red(const float* __restrict__ part,
    float* __restrict__ colsum)
{
    int x = blockIdx.x * 256 + threadIdx.x;
    const int S = BATCH * NH * NSRC;
    colsum[x] = part[x] + part[x + S] + part[x + 2 * S] + part[x + 3 * S];
}

// ---------------- pass B: waves split i; k/v LDS-shared; XCD-affine ----------------
// 1-D grid 1024: id%8==bh%8; per block: i-tile 64 (wave owns 16 rows), j-quarter loop
__global__ __launch_bounds__(256, 4) void pass_b(const u16* __restrict__ q,
    const u16* __restrict__ k, const u16* __restrict__ vTh, const u16* __restrict__ vTl,
    const float* __restrict__ colsum, float* __restrict__ pv, float* __restrict__ rs)
{
    int id = blockIdx.x;
    int slot = id >> 3;
    int bh = (id & 7) + 8 * (slot >> 6);
    int rem = slot & 63;
    int split = rem >> 4;        // 0..3
    int i0 = (rem & 15) * 64;    // 0..960
    int t = threadIdx.x, wave = t >> 6, lane = t & 63;
    const u16* qb = q + (size_t)bh * NSINK * HD;
    const u16* kb = k + (size_t)bh * NSRC * HD;
    const u16* vh = vTh + (size_t)bh * HD * NSRC;
    const u16* vl = vTl + (size_t)bh * HD * NSRC;

    __shared__ u16 Ks[64 * 64];
    __shared__ u16 Vhs[64 * 64];
    __shared__ u16 Vls[64 * 64];
    __shared__ alignas(16) u16 pbuf[4][16 * 72];

    // wave's q rows: i0 + wave*16 .. +16
    short8 qf[2];
    #pragma unroll
    for (int kc = 0; kc < 2; ++kc)
        qf[kc] = ldfrag(qb + (size_t)(i0 + wave * 16) * HD + kc * 32, HD, lane);

    f32x4 o[4] = {};
    float rsum[4] = {};
    for (int jt = 0; jt < 16; ++jt) {
        int j0 = split * (NSRC / 4) + jt * 64;
        stage_tile<64>(Ks,  kb + (size_t)j0 * HD, HD, t);
        stage_tile<64>(Vhs, vh + j0, NSRC, t);
        stage_tile<64>(Vls, vl + j0, NSRC, t);
        __syncthreads();   // drains global_load_lds (vmcnt) + protects LDS reuse
        float inv[4];
        #pragma unroll
        for (int jf = 0; jf < 4; ++jf)
            inv[jf] = fast_rcp(colsum[(size_t)bh * NSRC + j0 + jf * 16 + (lane & 15)]);
        f32x4 s[4] = {};
        #pragma unroll
        for (int kc = 0; kc < 2; ++kc)
            #pragma unroll
            for (int jf = 0; jf < 4; ++jf)
                s[jf] = mfma16(qf[kc], rdfrag(Ks, jf * 16, kc * 4, lane), s[jf]);
        #pragma unroll
        for (int jf = 0; jf < 4; ++jf) {
            float p0 = fast_exp2(s[jf][0]) * inv[jf];
            float p1 = fast_exp2(s[jf][1]) * inv[jf];
            float p2 = fast_exp2(s[jf][2]) * inv[jf];
            float p3 = fast_exp2(s[jf][3]) * inv[jf];
            rsum[0] += p0; rsum[1] += p1; rsum[2] += p2; rsum[3] += p3;
            u16* dst = &pbuf[wave][(size_t)((lane >> 4) * 4) * 72 + jf * 16 + (lane & 15)];
            dst[0]       = f2bf(p0);
            dst[72]      = f2bf(p1);
            dst[2 * 72]  = f2bf(p2);
            dst[3 * 72]  = f2bf(p3);
        }
        // PV: pbuf is wave-local (no barrier needed); Vh/Vl shared reads
        #pragma unroll
        for (int jc = 0; jc < 2; ++jc) {
            short8 pa = *(const short8*)&pbuf[wave][(size_t)(lane & 15) * 72 + jc * 32 + (lane >> 4) * 8];
            #pragma unroll
            for (int df = 0; df < 4; ++df) {
                o[df] = mfma16(pa, rdfrag(Vhs, df * 16, jc * 4, lane), o[df]);
                o[df] = mfma16(pa, rdfrag(Vls, df * 16, jc * 4, lane), o[df]);
            }
        }
        __syncthreads();   // before next jt overwrites Ks/Vhs/Vls
    }
    // rowsum: reduce across the 16 j-lanes
    #pragma unroll
    for (int r = 0; r < 4; ++r) {
        float v = rsum[r];
        v += __shfl_xor(v, 1, 64); v += __shfl_xor(v, 2, 64);
        v += __shfl_xor(v, 4, 64); v += __shfl_xor(v, 8, 64);
        if ((lane & 15) == 0)
            rs[((size_t)split * (BATCH * NH) + bh) * NSINK + i0 + wave * 16 + (lane >> 4) * 4 + r] = v;
    }
    // o write: wave owns its rows, direct store
    int b = bh >> 3, h = bh & 7;
    float* pvp = pv + (size_t)split * BATCH * NSINK * DIM;
    #pragma unroll
    for (int df = 0; df < 4; ++df)
        #pragma unroll
        for (int r = 0; r < 4; ++r) {
            int row = i0 + wave * 16 + (lane >> 4) * 4 + r;
            pvp[((size_t)(b * NSINK + row)) * DIM + h * HD + df * 16 + (lane & 15)] = o[df][r];
        }
}

// ---------------- finalize: a = (sum pv + eps*vsum)/(sum rs + Neps) -> split bf16 ----------------
__global__ __launch_bounds__(256) void finalize_pv(const float* __restrict__ pv,
    const float* __restrict__ rs, const float* __restrict__ vs,
    u16* __restrict__ ah, u16* __restrict__ al)
{
    const int M = BATCH * NSINK * DIM;
    const int R = BATCH * NH * NSINK;
    int idx = blockIdx.x * 256 + threadIdx.x;
    int m = idx >> 9, n = idx & 511;
    int b = m >> 10, i = m & 1023, h = n >> 6, d = n & 63;
    int bh = b * NH + h;
    float val = pv[idx] + pv[idx + M] + pv[idx + 2 * M] + pv[idx + 3 * M]
              + EPS * vs[bh * HD + d];
    float rsv = rs[bh * NSINK + i] + rs[R + bh * NSINK + i]
              + rs[2 * R + bh * NSINK + i] + rs[3 * R + bh * NSINK + i]
              + (float)NSRC * EPS;
    val /= rsv;
    u16 hh = f2bf(val);
    ah[idx] = hh;
    al[idx] = f2bf(val - bf2f(hh));
}

extern "C" void kernel_launch(void* const* d_in, const int* in_sizes, int n_in,
                              void* d_out, int out_size, void* d_ws, size_t ws_size,
                              hipStream_t stream) {
    (void)in_sizes; (void)n_in; (void)out_size;
    const float* sink    = (const float*)d_in[0];
    const float* source  = (const float*)d_in[1];
    const float* gamma_s = (const float*)d_in[2];
    const float* beta_s  = (const float*)d_in[3];
    const float* gamma_c = (const float*)d_in[4];
    const float* beta_c  = (const float*)d_in[5];
    const float* Wq      = (const float*)d_in[6];
    const float* bq      = (const float*)d_in[7];
    const float* Wkv     = (const float*)d_in[8];
    const float* bkv     = (const float*)d_in[9];
    const float* Wo      = (const float*)d_in[10];
    const float* bo      = (const float*)d_in[11];
    float* out = (float*)d_out;

    char* p = (char*)d_ws;
    auto carve = [&](size_t bytes) { char* r = p; p += (bytes + 255) & ~(size_t)255; return r; };
    u16* sh    = (u16*)carve(2048ull * 512 * 2);
    u16* sl    = (u16*)carve(2048ull * 512 * 2);
    u16* ch    = (u16*)carve(8192ull * 512 * 2);   // 8 MB
    u16* cl    = (u16*)carve(8192ull * 512 * 2);   // 8 MB (contiguous after ch)
    u16* wqTh  = (u16*)carve(512ull * 512 * 2);
    u16* wqTl  = (u16*)carve(512ull * 512 * 2);
    u16* wkvTh = (u16*)carve(1024ull * 512 * 2);
    u16* wkvTl = (u16*)carve(1024ull * 512 * 2);
    u16* woTh  = (u16*)carve(512ull * 512 * 2);
    u16* woTl  = (u16*)carve(512ull * 512 * 2);
    u16* qb    = (u16*)carve(16ull * 1024 * 64 * 2);
    u16* kb    = (u16*)carve(16ull * 4096 * 64 * 2);
    u16* vTh   = (u16*)carve(16ull * 64 * 4096 * 2);
    u16* vTl   = (u16*)carve(16ull * 64 * 4096 * 2);
    float* colsum  = (float*)carve(16ull * 4096 * 4);
    float* cs_part = (float*)carve(4ull * 16 * 4096 * 4);
    float* vs      = (float*)carve(1024ull * 4);
    float* rs      = (float*)carve(4ull * 16 * 1024 * 4);
    if ((size_t)(p - (char*)d_ws) > ws_size) return;
    // lifetime aliases: pv (16.78 MB, 4 splits) exactly over ch+cl (dead after KV gemm);
    // ah/al over sh/sl (dead after Q gemm)
    float* pv = (float*)ch;
    u16*   ah = sh;
    u16*   al = sl;

    ln_split<<<BATCH * NSINK, 256, 0, stream>>>(sink, gamma_s, beta_s, sh, sl);
    ln_split<<<BATCH * NSRC,  256, 0, stream>>>(source, gamma_c, beta_c, ch, cl);
    wt_split<<<512,  256, 0, stream>>>(Wq, 512, 512, wqTh, wqTl);
    wt_split<<<1024, 256, 0, stream>>>(Wkv, 512, 1024, wkvTh, wkvTl);
    wt_split<<<512,  256, 0, stream>>>(Wo, 512, 512, woTh, woTl);

    // Q: 1-term, 64x64 tiles
    gemm_lds<1, 64, 64><<<dim3(DIM / 64, BATCH * NSINK / 64), 256, 0, stream>>>(
        sh, nullptr, wqTh, nullptr, bq, 512, nullptr, qb, nullptr, nullptr);
    // KV: mixed 1/3-term, 128x128 tiles
    gemm_lds<2, 128, 128><<<dim3(2 * DIM / 128, BATCH * NSRC / 128), 256, 0, stream>>>(
        ch, cl, wkvTh, wkvTl, bkv, 512, nullptr, kb, vTh, vTl);

    vsum_k<<<1024, 256, 0, stream>>>(vTh, vTl, vs);
    pass_a<<<1024, 256, 0, stream>>>(qb, kb, cs_part);
    csum_red<<<BATCH * NH * NSRC / 256, 256, 0, stream>>>(cs_part, colsum);
    pass_b<<<1024, 256, 0, stream>>>(qb, kb, vTh, vTl, colsum, pv, rs);
    finalize_pv<<<4096, 256, 0, stream>>>(pv, rs, vs, ah, al);

    // out: 3-term, 64x64 tiles
    gemm_lds<0, 64, 64><<<dim3(DIM / 64, BATCH * NSINK / 64), 256, 0, stream>>>(
        ah, al, woTh, woTl, bo, 512, out, nullptr, nullptr, nullptr);
}

// Round 7
// 143.344 us; speedup vs baseline: 1.8687x; 1.3729x over previous
//
#include <hip/hip_runtime.h>
#include <hip/hip_bf16.h>
#include <math.h>

#define EPS 1e-6f
#define NSINK 1024
#define NSRC 4096
#define DIM 512
#define NH 8
#define HD 64
#define BATCH 2
// fold (d^-0.5 = 1/8) * log2(e) into q so sim exp is a single exp2
#define QSCALE 0.18033688011112042f

typedef unsigned short u16;
typedef __attribute__((ext_vector_type(8))) short short8;
typedef __attribute__((ext_vector_type(4))) float f32x4;

__device__ inline float fast_exp2(float x) {
#if __has_builtin(__builtin_amdgcn_exp2f)
    return __builtin_amdgcn_exp2f(x);
#else
    return exp2f(x);
#endif
}
__device__ inline float fast_rcp(float x) {
#if __has_builtin(__builtin_amdgcn_rcpf)
    return __builtin_amdgcn_rcpf(x);
#else
    return 1.0f / x;
#endif
}
__device__ inline u16 f2bf(float x) {
    union { float f; unsigned u; } v; v.f = x;
    unsigned r = v.u + 0x7fffu + ((v.u >> 16) & 1u);
    return (u16)(r >> 16);
}
__device__ inline float bf2f(u16 h) {
    union { unsigned u; float f; } v; v.u = ((unsigned)h) << 16;
    return v.f;
}
__device__ inline f32x4 mfma16(short8 a, short8 b, f32x4 c) {
    return __builtin_amdgcn_mfma_f32_16x16x32_bf16(a, b, c, 0, 0, 0);
}
// direct-from-global fragment loader
__device__ inline short8 ldfrag(const u16* base, int stride, int lane) {
    return *(const short8*)(base + (size_t)(lane & 15) * stride + ((lane >> 4) << 3));
}

// async global->LDS, 16B per lane
__device__ inline void gld16(const u16* g, u16* l) {
    __builtin_amdgcn_global_load_lds(
        (const __attribute__((address_space(1))) unsigned*)g,
        (__attribute__((address_space(3))) unsigned*)l, 16, 0, 0);
}

// stage a [TM][64] bf16 tile from gsrc (row-major, stride K);
// LDS linear dest; global source inverse-swizzled (c ^= m&7).
template<int TM>
__device__ inline void stage_tile(u16* lds, const u16* gsrc, int K, int t) {
    #pragma unroll
    for (int it = 0; it < TM / 32; ++it) {
        int m = it * 32 + (t >> 3);
        int c = (t & 7) ^ (m & 7);
        gld16(gsrc + (size_t)m * K + c * 8,
              lds + it * 2048 + (t >> 6) * 512);
    }
}
// swizzled fragment read
__device__ inline short8 rdfrag(const u16* tile, int fbase, int cbase, int lane) {
    int m = fbase + (lane & 15);
    int c = (cbase + (lane >> 4)) ^ (m & 7);
    return *(const short8*)(tile + (size_t)m * 64 + c * 8);
}

// ---------------- LayerNorm (row=512) -> bf16 ----------------
__global__ __launch_bounds__(256) void ln_bf16(const float* __restrict__ x,
    const float* __restrict__ g, const float* __restrict__ be,
    u16* __restrict__ yh)
{
    int row = blockIdx.x;
    int t = threadIdx.x;
    const float* xr = x + (size_t)row * DIM;
    float v0 = xr[t], v1 = xr[t + 256];
    float s = v0 + v1, sq = v0 * v0 + v1 * v1;
    #pragma unroll
    for (int off = 32; off > 0; off >>= 1) {
        s  += __shfl_down(s, off, 64);
        sq += __shfl_down(sq, off, 64);
    }
    __shared__ float rs[4], rq[4];
    int wave = t >> 6;
    if ((t & 63) == 0) { rs[wave] = s; rq[wave] = sq; }
    __syncthreads();
    s  = rs[0] + rs[1] + rs[2] + rs[3];
    sq = rq[0] + rq[1] + rq[2] + rq[3];
    float mu = s * (1.0f / DIM);
    float var = sq * (1.0f / DIM) - mu * mu;
    float a = var + EPS;
    float r = rsqrtf(a);
    r = r * (1.5f - 0.5f * a * r * r);
    size_t o = (size_t)row * DIM;
    yh[o + t]       = f2bf((v0 - mu) * r * g[t] + be[t]);
    yh[o + t + 256] = f2bf((v1 - mu) * r * g[t + 256] + be[t + 256]);
}

// ---------------- weight transpose: W[K][N] -> T[N][K] bf16 ----------------
__global__ __launch_bounds__(256) void wt_t(const float* __restrict__ W, int K, int N,
    u16* __restrict__ Th)
{
    int n = blockIdx.x;
    for (int k = threadIdx.x; k < K; k += 256)
        Th[(size_t)n * K + k] = f2bf(W[(size_t)k * N + n]);
}

// ---------------- 1-term 2-phase LDS-dbuf MFMA GEMM: C = A @ BT^T + bias ----------------
// MODE 0: C fp32 row-major. MODE 1: q bf16 [bh][i][d] * QSCALE.
// MODE 2: n<512 -> k bf16 [bh][j][d]; n>=512 -> vT bf16 [bh*64+d][j].
template<int MODE, int TM, int TN>
__global__ __launch_bounds__(256) void gemm1(
    const u16* __restrict__ A, const u16* __restrict__ BT,
    const float* __restrict__ bias, int K,
    float* __restrict__ cf, u16* __restrict__ o1, u16* __restrict__ o2)
{
    constexpr int FM = TM / 32, FN = TN / 32;
    __shared__ u16 As[2][TM * 64];
    __shared__ u16 Bs[2][TN * 64];
    int t = threadIdx.x;
    int wave = t >> 6, lane = t & 63;
    int wr = wave >> 1, wc = wave & 1;
    int m0 = blockIdx.y * TM, n0 = blockIdx.x * TN;

    f32x4 acc[FM][FN] = {};
    // prologue: stage tile 0
    stage_tile<TM>(As[0], A + (size_t)m0 * K, K, t);
    stage_tile<TN>(Bs[0], BT + (size_t)n0 * K, K, t);
    __syncthreads();
    int nt = K >> 6;
    int cur = 0;
    for (int kt = 0; kt < nt; ++kt) {
        if (kt + 1 < nt) {  // prefetch next K-tile into other buffer
            stage_tile<TM>(As[cur ^ 1], A + (size_t)m0 * K + (kt + 1) * 64, K, t);
            stage_tile<TN>(Bs[cur ^ 1], BT + (size_t)n0 * K + (kt + 1) * 64, K, t);
        }
        #pragma unroll
        for (int kk = 0; kk < 2; ++kk) {
            short8 af[FM], bf[FN];
            #pragma unroll
            for (int f = 0; f < FM; ++f)
                af[f] = rdfrag(As[cur], wr * (TM / 2) + f * 16, kk * 4, lane);
            #pragma unroll
            for (int f = 0; f < FN; ++f)
                bf[f] = rdfrag(Bs[cur], wc * (TN / 2) + f * 16, kk * 4, lane);
            #pragma unroll
            for (int i = 0; i < FM; ++i)
                #pragma unroll
                for (int j = 0; j < FN; ++j)
                    acc[i][j] = mfma16(af[i], bf[j], acc[i][j]);
        }
        __syncthreads();   // drains vmcnt (next tile landed) + guards buffer reuse
        cur ^= 1;
    }

    #pragma unroll
    for (int i = 0; i < FM; ++i)
        #pragma unroll
        for (int j = 0; j < FN; ++j)
            #pragma unroll
            for (int r = 0; r < 4; ++r) {
                int m = m0 + wr * (TM / 2) + i * 16 + (lane >> 4) * 4 + r;
                int n = n0 + wc * (TN / 2) + j * 16 + (lane & 15);
                float v = acc[i][j][r] + bias[n];
                if (MODE == 0) {
                    cf[(size_t)m * DIM + n] = v;
                } else if (MODE == 1) {
                    int b = m >> 10, ii = m & 1023;
                    int h = n >> 6, d = n & 63;
                    o1[((size_t)(b * NH + h) * NSINK + ii) * HD + d] = f2bf(v * QSCALE);
                } else {
                    int b = m >> 12, jj = m & 4095;
                    if (n < DIM) {
                        int h = n >> 6, d = n & 63;
                        o1[((size_t)(b * NH + h) * NSRC + jj) * HD + d] = f2bf(v);
                    } else {
                        int nn = n - DIM;
                        int h = nn >> 6, d = nn & 63;
                        o2[((size_t)(b * NH + h) * HD + d) * NSRC + jj] = f2bf(v);
                    }
                }
            }
}

// ---------------- vsum[bh*64+d] = sum_j v ----------------
__global__ __launch_bounds__(256) void vsum_k(const u16* __restrict__ vTh,
    float* __restrict__ vs)
{
    int row = blockIdx.x;
    const u16* ph = vTh + (size_t)row * NSRC;
    float s = 0.f;
    for (int j = threadIdx.x; j < NSRC; j += 256) s += bf2f(ph[j]);
    #pragma unroll
    for (int off = 32; off > 0; off >>= 1) s += __shfl_down(s, off, 64);
    __shared__ float r4[4];
    if ((threadIdx.x & 63) == 0) r4[threadIdx.x >> 6] = s;
    __syncthreads();
    if (threadIdx.x == 0) vs[row] = r4[0] + r4[1] + r4[2] + r4[3];
}

// ---------------- pass A: colsum_part[ic][bh][j] = sum_{i chunk} exp2(q.k) ----------------
// 1-D grid 1024, XCD-affine decode: id%8 == bh%8
__global__ __launch_bounds__(256, 4) void pass_a(const u16* __restrict__ q,
    const u16* __restrict__ k, float* __restrict__ part)
{
    int id = blockIdx.x;
    int slot = id >> 3;
    int bh = (id & 7) + 8 * (slot >> 6);
    int rem = slot & 63;
    int ic = rem >> 4;
    int wave = threadIdx.x >> 6, lane = threadIdx.x & 63;
    int j0 = (rem & 15) * 256 + wave * 64;
    const u16* qb = q + (size_t)bh * NSINK * HD;
    const u16* kb = k + (size_t)bh * NSRC * HD;
    short8 kf[4][2];
    #pragma unroll
    for (int jf = 0; jf < 4; ++jf)
        #pragma unroll
        for (int kc = 0; kc < 2; ++kc)
            kf[jf][kc] = ldfrag(kb + (size_t)(j0 + jf * 16) * HD + kc * 32, HD, lane);
    float csum[4] = {};
    for (int ii = 0; ii < 4; ++ii) {
        int ibase = ic * 256 + ii * 64;
        #pragma unroll
        for (int f = 0; f < 4; ++f) {
            short8 q0 = ldfrag(qb + (size_t)(ibase + f * 16) * HD, HD, lane);
            short8 q1 = ldfrag(qb + (size_t)(ibase + f * 16) * HD + 32, HD, lane);
            f32x4 s[4] = {};
            #pragma unroll
            for (int jf = 0; jf < 4; ++jf) s[jf] = mfma16(q0, kf[jf][0], s[jf]);
            #pragma unroll
            for (int jf = 0; jf < 4; ++jf) s[jf] = mfma16(q1, kf[jf][1], s[jf]);
            #pragma unroll
            for (int jf = 0; jf < 4; ++jf)
                csum[jf] += fast_exp2(s[jf][0]) + fast_exp2(s[jf][1])
                          + fast_exp2(s[jf][2]) + fast_exp2(s[jf][3]);
        }
    }
    #pragma unroll
    for (int jf = 0; jf < 4; ++jf) {
        csum[jf] += __shfl_xor(csum[jf], 16, 64);
        csum[jf] += __shfl_xor(csum[jf], 32, 64);
    }
    if (lane < 16)
        #pragma unroll
        for (int jf = 0; jf < 4; ++jf)
            part[((size_t)ic * BATCH * NH + bh) * NSRC + j0 + jf * 16 + lane] = csum[jf];
}

// colsum[x] = sum_ic part[ic][x]
__global__ __launch_bounds__(256) void csum_red(const float* __restrict__ part,
    float* __restrict__ colsum)
{
    int x = blockIdx.x * 256 + threadIdx.x;
    const int S = BATCH * NH * NSRC;
    colsum[x] = part[x] + part[x + S] + part[x + 2 * S] + part[x + 3 * S];
}

// ---------------- pass B: waves split i; k/v LDS-shared; XCD-affine ----------------
__global__ __launch_bounds__(256, 4) void pass_b(const u16* __restrict__ q,
    const u16* __restrict__ k, const u16* __restrict__ vTh,
    const float* __restrict__ colsum, float* __restrict__ pv, float* __restrict__ rs)
{
    int id = blockIdx.x;
    int slot = id >> 3;
    int bh = (id & 7) + 8 * (slot >> 6);
    int rem = slot & 63;
    int split = rem >> 4;        // 0..3
    int i0 = (rem & 15) * 64;    // 0..960
    int t = threadIdx.x, wave = t >> 6, lane = t & 63;
    const u16* qb = q + (size_t)bh * NSINK * HD;
    const u16* kb = k + (size_t)bh * NSRC * HD;
    const u16* vh = vTh + (size_t)bh * HD * NSRC;

    __shared__ u16 Ks[64 * 64];
    __shared__ u16 Vhs[64 * 64];
    __shared__ alignas(16) u16 pbuf[4][16 * 72];

    short8 qf[2];
    #pragma unroll
    for (int kc = 0; kc < 2; ++kc)
        qf[kc] = ldfrag(qb + (size_t)(i0 + wave * 16) * HD + kc * 32, HD, lane);

    f32x4 o[4] = {};
    float rsum[4] = {};
    for (int jt = 0; jt < 16; ++jt) {
        int j0 = split * (NSRC / 4) + jt * 64;
        stage_tile<64>(Ks,  kb + (size_t)j0 * HD, HD, t);
        stage_tile<64>(Vhs, vh + j0, NSRC, t);
        __syncthreads();
        float inv[4];
        #pragma unroll
        for (int jf = 0; jf < 4; ++jf)
            inv[jf] = fast_rcp(colsum[(size_t)bh * NSRC + j0 + jf * 16 + (lane & 15)]);
        f32x4 s[4] = {};
        #pragma unroll
        for (int kc = 0; kc < 2; ++kc)
            #pragma unroll
            for (int jf = 0; jf < 4; ++jf)
                s[jf] = mfma16(qf[kc], rdfrag(Ks, jf * 16, kc * 4, lane), s[jf]);
        #pragma unroll
        for (int jf = 0; jf < 4; ++jf) {
            float p0 = fast_exp2(s[jf][0]) * inv[jf];
            float p1 = fast_exp2(s[jf][1]) * inv[jf];
            float p2 = fast_exp2(s[jf][2]) * inv[jf];
            float p3 = fast_exp2(s[jf][3]) * inv[jf];
            rsum[0] += p0; rsum[1] += p1; rsum[2] += p2; rsum[3] += p3;
            u16* dst = &pbuf[wave][(size_t)((lane >> 4) * 4) * 72 + jf * 16 + (lane & 15)];
            dst[0]       = f2bf(p0);
            dst[72]      = f2bf(p1);
            dst[2 * 72]  = f2bf(p2);
            dst[3 * 72]  = f2bf(p3);
        }
        // PV: pbuf is wave-local (no barrier needed)
        #pragma unroll
        for (int jc = 0; jc < 2; ++jc) {
            short8 pa = *(const short8*)&pbuf[wave][(size_t)(lane & 15) * 72 + jc * 32 + (lane >> 4) * 8];
            #pragma unroll
            for (int df = 0; df < 4; ++df)
                o[df] = mfma16(pa, rdfrag(Vhs, df * 16, jc * 4, lane), o[df]);
        }
        __syncthreads();   // before next jt overwrites Ks/Vhs
    }
    #pragma unroll
    for (int r = 0; r < 4; ++r) {
        float v = rsum[r];
        v += __shfl_xor(v, 1, 64); v += __shfl_xor(v, 2, 64);
        v += __shfl_xor(v, 4, 64); v += __shfl_xor(v, 8, 64);
        if ((lane & 15) == 0)
            rs[((size_t)split * (BATCH * NH) + bh) * NSINK + i0 + wave * 16 + (lane >> 4) * 4 + r] = v;
    }
    int b = bh >> 3, h = bh & 7;
    float* pvp = pv + (size_t)split * BATCH * NSINK * DIM;
    #pragma unroll
    for (int df = 0; df < 4; ++df)
        #pragma unroll
        for (int r = 0; r < 4; ++r) {
            int row = i0 + wave * 16 + (lane >> 4) * 4 + r;
            pvp[((size_t)(b * NSINK + row)) * DIM + h * HD + df * 16 + (lane & 15)] = o[df][r];
        }
}

// ---------------- finalize: a = (sum pv + eps*vsum)/(sum rs + Neps) -> bf16 ----------------
__global__ __launch_bounds__(256) void finalize_pv(const float* __restrict__ pv,
    const float* __restrict__ rs, const float* __restrict__ vs,
    u16* __restrict__ ab)
{
    const int M = BATCH * NSINK * DIM;
    const int R = BATCH * NH * NSINK;
    int idx = blockIdx.x * 256 + threadIdx.x;
    int m = idx >> 9, n = idx & 511;
    int b = m >> 10, i = m & 1023, h = n >> 6, d = n & 63;
    int bh = b * NH + h;
    float val = pv[idx] + pv[idx + M] + pv[idx + 2 * M] + pv[idx + 3 * M]
              + EPS * vs[bh * HD + d];
    float rsv = rs[bh * NSINK + i] + rs[R + bh * NSINK + i]
              + rs[2 * R + bh * NSINK + i] + rs[3 * R + bh * NSINK + i]
              + (float)NSRC * EPS;
    ab[idx] = f2bf(val / rsv);
}

extern "C" void kernel_launch(void* const* d_in, const int* in_sizes, int n_in,
                              void* d_out, int out_size, void* d_ws, size_t ws_size,
                              hipStream_t stream) {
    (void)in_sizes; (void)n_in; (void)out_size;
    const float* sink    = (const float*)d_in[0];
    const float* source  = (const float*)d_in[1];
    const float* gamma_s = (const float*)d_in[2];
    const float* beta_s  = (const float*)d_in[3];
    const float* gamma_c = (const float*)d_in[4];
    const float* beta_c  = (const float*)d_in[5];
    const float* Wq      = (const float*)d_in[6];
    const float* bq      = (const float*)d_in[7];
    const float* Wkv     = (const float*)d_in[8];
    const float* bkv     = (const float*)d_in[9];
    const float* Wo      = (const float*)d_in[10];
    const float* bo      = (const float*)d_in[11];
    float* out = (float*)d_out;

    char* p = (char*)d_ws;
    auto carve = [&](size_t bytes) { char* r = p; p += (bytes + 255) & ~(size_t)255; return r; };
    u16* sh    = (u16*)carve(2048ull * 512 * 2);       // LN'd sink
    u16* ch    = (u16*)carve(8192ull * 512 * 2);       // LN'd source
    u16* wqT   = (u16*)carve(512ull * 512 * 2);
    u16* wkvT  = (u16*)carve(1024ull * 512 * 2);
    u16* woT   = (u16*)carve(512ull * 512 * 2);
    u16* qb    = (u16*)carve(16ull * 1024 * 64 * 2);
    u16* kb    = (u16*)carve(16ull * 4096 * 64 * 2);
    u16* vTh   = (u16*)carve(16ull * 64 * 4096 * 2);
    float* colsum  = (float*)carve(16ull * 4096 * 4);
    float* cs_part = (float*)carve(4ull * 16 * 4096 * 4);
    float* vs      = (float*)carve(1024ull * 4);
    float* rs      = (float*)carve(4ull * 16 * 1024 * 4);
    float* pv      = (float*)carve(4ull * 2048 * 512 * 4);
    u16*   ab      = (u16*)carve(2048ull * 512 * 2);
    if ((size_t)(p - (char*)d_ws) > ws_size) return;

    ln_bf16<<<BATCH * NSINK, 256, 0, stream>>>(sink, gamma_s, beta_s, sh);
    ln_bf16<<<BATCH * NSRC,  256, 0, stream>>>(source, gamma_c, beta_c, ch);
    wt_t<<<512,  256, 0, stream>>>(Wq, 512, 512, wqT);
    wt_t<<<1024, 256, 0, stream>>>(Wkv, 512, 1024, wkvT);
    wt_t<<<512,  256, 0, stream>>>(Wo, 512, 512, woT);

    // Q: 64x64 tiles
    gemm1<1, 64, 64><<<dim3(DIM / 64, BATCH * NSINK / 64), 256, 0, stream>>>(
        sh, wqT, bq, 512, nullptr, qb, nullptr);
    // KV: 128x128 tiles
    gemm1<2, 128, 128><<<dim3(2 * DIM / 128, BATCH * NSRC / 128), 256, 0, stream>>>(
        ch, wkvT, bkv, 512, nullptr, kb, vTh);

    vsum_k<<<1024, 256, 0, stream>>>(vTh, vs);
    pass_a<<<1024, 256, 0, stream>>>(qb, kb, cs_part);
    csum_red<<<BATCH * NH * NSRC / 256, 256, 0, stream>>>(cs_part, colsum);
    pass_b<<<1024, 256, 0, stream>>>(qb, kb, vTh, colsum, pv, rs);
    finalize_pv<<<4096, 256, 0, stream>>>(pv, rs, vs, ab);

    // out: 64x64 tiles
    gemm1<0, 64, 64><<<dim3(DIM / 64, BATCH * NSINK / 64), 256, 0, stream>>>(
        ab, woT, bo, 512, out, nullptr, nullptr);
}

// Round 8
// 142.991 us; speedup vs baseline: 1.8733x; 1.0025x over previous
//
#include <hip/hip_runtime.h>
#include <hip/hip_bf16.h>
#include <math.h>

#define EPS 1e-6f
#define NSINK 1024
#define NSRC 4096
#define DIM 512
#define NH 8
#define HD 64
#define BATCH 2
#define VROWS 96   // extended V: 0..63 = v/cs, 64 = 1/cs, 65..95 = 0
// fold (d^-0.5 = 1/8) * log2(e) into q so sim exp is a single exp2
#define QSCALE 0.18033688011112042f

typedef unsigned short u16;
typedef __attribute__((ext_vector_type(8))) short short8;
typedef __attribute__((ext_vector_type(4))) float f32x4;

__device__ inline float fast_exp2(float x) {
#if __has_builtin(__builtin_amdgcn_exp2f)
    return __builtin_amdgcn_exp2f(x);
#else
    return exp2f(x);
#endif
}
__device__ inline float fast_rcp(float x) {
#if __has_builtin(__builtin_amdgcn_rcpf)
    return __builtin_amdgcn_rcpf(x);
#else
    return 1.0f / x;
#endif
}
__device__ inline u16 f2bf(float x) {
    union { float f; unsigned u; } v; v.f = x;
    unsigned r = v.u + 0x7fffu + ((v.u >> 16) & 1u);
    return (u16)(r >> 16);
}
__device__ inline float bf2f(u16 h) {
    union { unsigned u; float f; } v; v.u = ((unsigned)h) << 16;
    return v.f;
}
// pack 2 f32 -> 2 bf16 (RTNE) in one u32; lowers to v_cvt_pk_bf16_f32
__device__ inline unsigned pk_bf16(float a, float b) {
    union { __hip_bfloat162 h; unsigned u; } v;
    v.h = __float22bfloat162_rn(make_float2(a, b));
    return v.u;
}
__device__ inline f32x4 mfma16(short8 a, short8 b, f32x4 c) {
    return __builtin_amdgcn_mfma_f32_16x16x32_bf16(a, b, c, 0, 0, 0);
}
// direct-from-global fragment loader
__device__ inline short8 ldfrag(const u16* base, int stride, int lane) {
    return *(const short8*)(base + (size_t)(lane & 15) * stride + ((lane >> 4) << 3));
}

// async global->LDS, 16B per lane
__device__ inline void gld16(const u16* g, u16* l) {
    __builtin_amdgcn_global_load_lds(
        (const __attribute__((address_space(1))) unsigned*)g,
        (__attribute__((address_space(3))) unsigned*)l, 16, 0, 0);
}

// stage a [TM][64] bf16 tile from gsrc (row-major, stride K);
// LDS linear dest; global source inverse-swizzled (c ^= m&7).
template<int TM>
__device__ inline void stage_tile(u16* lds, const u16* gsrc, int K, int t) {
    #pragma unroll
    for (int it = 0; it < TM / 32; ++it) {
        int m = it * 32 + (t >> 3);
        int c = (t & 7) ^ (m & 7);
        gld16(gsrc + (size_t)m * K + c * 8,
              lds + it * 2048 + (t >> 6) * 512);
    }
}
// swizzled fragment read
__device__ inline short8 rdfrag(const u16* tile, int fbase, int cbase, int lane) {
    int m = fbase + (lane & 15);
    int c = (cbase + (lane >> 4)) ^ (m & 7);
    return *(const short8*)(tile + (size_t)m * 64 + c * 8);
}

// ---------------- LayerNorm (row=512) -> bf16 ----------------
__global__ __launch_bounds__(256) void ln_bf16(const float* __restrict__ x,
    const float* __restrict__ g, const float* __restrict__ be,
    u16* __restrict__ yh)
{
    int row = blockIdx.x;
    int t = threadIdx.x;
    const float* xr = x + (size_t)row * DIM;
    float v0 = xr[t], v1 = xr[t + 256];
    float s = v0 + v1, sq = v0 * v0 + v1 * v1;
    #pragma unroll
    for (int off = 32; off > 0; off >>= 1) {
        s  += __shfl_down(s, off, 64);
        sq += __shfl_down(sq, off, 64);
    }
    __shared__ float rs[4], rq[4];
    int wave = t >> 6;
    if ((t & 63) == 0) { rs[wave] = s; rq[wave] = sq; }
    __syncthreads();
    s  = rs[0] + rs[1] + rs[2] + rs[3];
    sq = rq[0] + rq[1] + rq[2] + rq[3];
    float mu = s * (1.0f / DIM);
    float var = sq * (1.0f / DIM) - mu * mu;
    float a = var + EPS;
    float r = rsqrtf(a);
    r = r * (1.5f - 0.5f * a * r * r);
    size_t o = (size_t)row * DIM;
    yh[o + t]       = f2bf((v0 - mu) * r * g[t] + be[t]);
    yh[o + t + 256] = f2bf((v1 - mu) * r * g[t + 256] + be[t + 256]);
}

// ---------------- weight transpose: W[K][N] -> T[N][K] bf16 ----------------
__global__ __launch_bounds__(256) void wt_t(const float* __restrict__ W, int K, int N,
    u16* __restrict__ Th)
{
    int n = blockIdx.x;
    for (int k = threadIdx.x; k < K; k += 256)
        Th[(size_t)n * K + k] = f2bf(W[(size_t)k * N + n]);
}

// ---------------- 1-term 2-phase LDS-dbuf MFMA GEMM: C = A @ BT^T + bias ----------------
// MODE 0: C fp32 row-major. MODE 1: q bf16 [bh][i][d] * QSCALE.
// MODE 2: n<512 -> k bf16 [bh][j][d]; n>=512 -> vT bf16 [bh*64+d][j].
template<int MODE, int TM, int TN>
__global__ __launch_bounds__(256) void gemm1(
    const u16* __restrict__ A, const u16* __restrict__ BT,
    const float* __restrict__ bias, int K,
    float* __restrict__ cf, u16* __restrict__ o1, u16* __restrict__ o2)
{
    constexpr int FM = TM / 32, FN = TN / 32;
    __shared__ u16 As[2][TM * 64];
    __shared__ u16 Bs[2][TN * 64];
    int t = threadIdx.x;
    int wave = t >> 6, lane = t & 63;
    int wr = wave >> 1, wc = wave & 1;
    int m0 = blockIdx.y * TM, n0 = blockIdx.x * TN;

    f32x4 acc[FM][FN] = {};
    stage_tile<TM>(As[0], A + (size_t)m0 * K, K, t);
    stage_tile<TN>(Bs[0], BT + (size_t)n0 * K, K, t);
    __syncthreads();
    int nt = K >> 6;
    int cur = 0;
    for (int kt = 0; kt < nt; ++kt) {
        if (kt + 1 < nt) {
            stage_tile<TM>(As[cur ^ 1], A + (size_t)m0 * K + (kt + 1) * 64, K, t);
            stage_tile<TN>(Bs[cur ^ 1], BT + (size_t)n0 * K + (kt + 1) * 64, K, t);
        }
        #pragma unroll
        for (int kk = 0; kk < 2; ++kk) {
            short8 af[FM], bf[FN];
            #pragma unroll
            for (int f = 0; f < FM; ++f)
                af[f] = rdfrag(As[cur], wr * (TM / 2) + f * 16, kk * 4, lane);
            #pragma unroll
            for (int f = 0; f < FN; ++f)
                bf[f] = rdfrag(Bs[cur], wc * (TN / 2) + f * 16, kk * 4, lane);
            #pragma unroll
            for (int i = 0; i < FM; ++i)
                #pragma unroll
                for (int j = 0; j < FN; ++j)
                    acc[i][j] = mfma16(af[i], bf[j], acc[i][j]);
        }
        __syncthreads();
        cur ^= 1;
    }

    #pragma unroll
    for (int i = 0; i < FM; ++i)
        #pragma unroll
        for (int j = 0; j < FN; ++j)
            #pragma unroll
            for (int r = 0; r < 4; ++r) {
                int m = m0 + wr * (TM / 2) + i * 16 + (lane >> 4) * 4 + r;
                int n = n0 + wc * (TN / 2) + j * 16 + (lane & 15);
                float v = acc[i][j][r] + bias[n];
                if (MODE == 0) {
                    cf[(size_t)m * DIM + n] = v;
                } else if (MODE == 1) {
                    int b = m >> 10, ii = m & 1023;
                    int h = n >> 6, d = n & 63;
                    o1[((size_t)(b * NH + h) * NSINK + ii) * HD + d] = f2bf(v * QSCALE);
                } else {
                    int b = m >> 12, jj = m & 4095;
                    if (n < DIM) {
                        int h = n >> 6, d = n & 63;
                        o1[((size_t)(b * NH + h) * NSRC + jj) * HD + d] = f2bf(v);
                    } else {
                        int nn = n - DIM;
                        int h = nn >> 6, d = nn & 63;
                        o2[((size_t)(b * NH + h) * HD + d) * NSRC + jj] = f2bf(v);
                    }
                }
            }
}

// ---------------- vsum[bh*64+d] = sum_j v (original v, for the EPS term) ----------------
__global__ __launch_bounds__(256) void vsum_k(const u16* __restrict__ vTh,
    float* __restrict__ vs)
{
    int row = blockIdx.x;
    const u16* ph = vTh + (size_t)row * NSRC;
    float s = 0.f;
    for (int j = threadIdx.x; j < NSRC; j += 256) s += bf2f(ph[j]);
    #pragma unroll
    for (int off = 32; off > 0; off >>= 1) s += __shfl_down(s, off, 64);
    __shared__ float r4[4];
    if ((threadIdx.x & 63) == 0) r4[threadIdx.x >> 6] = s;
    __syncthreads();
    if (threadIdx.x == 0) vs[row] = r4[0] + r4[1] + r4[2] + r4[3];
}

// ---------------- pass A: colsum_part[ic][bh][j] = sum_{i chunk} exp2(q.k) ----------------
__global__ __launch_bounds__(256, 4) void pass_a(const u16* __restrict__ q,
    const u16* __restrict__ k, float* __restrict__ part)
{
    int id = blockIdx.x;
    int slot = id >> 3;
    int bh = (id & 7) + 8 * (slot >> 6);
    int rem = slot & 63;
    int ic = rem >> 4;
    int wave = threadIdx.x >> 6, lane = threadIdx.x & 63;
    int j0 = (rem & 15) * 256 + wave * 64;
    const u16* qb = q + (size_t)bh * NSINK * HD;
    const u16* kb = k + (size_t)bh * NSRC * HD;
    short8 kf[4][2];
    #pragma unroll
    for (int jf = 0; jf < 4; ++jf)
        #pragma unroll
        for (int kc = 0; kc < 2; ++kc)
            kf[jf][kc] = ldfrag(kb + (size_t)(j0 + jf * 16) * HD + kc * 32, HD, lane);
    float csum[4] = {};
    for (int ii = 0; ii < 4; ++ii) {
        int ibase = ic * 256 + ii * 64;
        #pragma unroll
        for (int f = 0; f < 4; ++f) {
            short8 q0 = ldfrag(qb + (size_t)(ibase + f * 16) * HD, HD, lane);
            short8 q1 = ldfrag(qb + (size_t)(ibase + f * 16) * HD + 32, HD, lane);
            f32x4 s[4] = {};
            #pragma unroll
            for (int jf = 0; jf < 4; ++jf) s[jf] = mfma16(q0, kf[jf][0], s[jf]);
            #pragma unroll
            for (int jf = 0; jf < 4; ++jf) s[jf] = mfma16(q1, kf[jf][1], s[jf]);
            #pragma unroll
            for (int jf = 0; jf < 4; ++jf)
                csum[jf] += fast_exp2(s[jf][0]) + fast_exp2(s[jf][1])
                          + fast_exp2(s[jf][2]) + fast_exp2(s[jf][3]);
        }
    }
    #pragma unroll
    for (int jf = 0; jf < 4; ++jf) {
        csum[jf] += __shfl_xor(csum[jf], 16, 64);
        csum[jf] += __shfl_xor(csum[jf], 32, 64);
    }
    if (lane < 16)
        #pragma unroll
        for (int jf = 0; jf < 4; ++jf)
            part[((size_t)ic * BATCH * NH + bh) * NSRC + j0 + jf * 16 + lane] = csum[jf];
}

// colsum[x] = sum_ic part[ic][x]
__global__ __launch_bounds__(256) void csum_red(const float* __restrict__ part,
    float* __restrict__ colsum)
{
    int x = blockIdx.x * 256 + threadIdx.x;
    const int S = BATCH * NH * NSRC;
    colsum[x] = part[x] + part[x + S] + part[x + 2 * S] + part[x + 3 * S];
}

// ---------------- vscale: Vext[bh][d][j]; d<64: v/cs, d==64: 1/cs, d>64: 0 ----------------
__global__ __launch_bounds__(256) void vscale(const u16* __restrict__ vTh,
    const float* __restrict__ colsum, u16* __restrict__ vT2)
{
    int d = blockIdx.x;   // 0..95
    int bh = blockIdx.y;  // 0..15
    u16* dst = vT2 + ((size_t)bh * VROWS + d) * NSRC;
    if (d > 64) {
        for (int j = threadIdx.x; j < NSRC; j += 256) dst[j] = 0;
        return;
    }
    const float* cs = colsum + (size_t)bh * NSRC;
    if (d == 64) {
        for (int j = threadIdx.x; j < NSRC; j += 256) dst[j] = f2bf(fast_rcp(cs[j]));
    } else {
        const u16* src = vTh + ((size_t)bh * HD + d) * NSRC;
        for (int j = threadIdx.x; j < NSRC; j += 256)
            dst[j] = f2bf(bf2f(src[j]) * fast_rcp(cs[j]));
    }
}

// ---------------- pass B: P = exp2(KQ^T) bf16; O = P·Vext (rowsum = extra row) ----------------
// 1-D grid 1024: id%8==bh%8; waves split i (16 rows each); j-quarter loop
__global__ __launch_bounds__(256, 4) void pass_b(const u16* __restrict__ q,
    const u16* __restrict__ k, const u16* __restrict__ vT2,
    float* __restrict__ pv, float* __restrict__ rs)
{
    int id = blockIdx.x;
    int slot = id >> 3;
    int bh = (id & 7) + 8 * (slot >> 6);
    int rem = slot & 63;
    int split = rem >> 4;        // 0..3
    int i0 = (rem & 15) * 64;    // 0..960
    int t = threadIdx.x, wave = t >> 6, lane = t & 63;
    const u16* qb = q + (size_t)bh * NSINK * HD;
    const u16* kb = k + (size_t)bh * NSRC * HD;
    const u16* vb = vT2 + (size_t)bh * VROWS * NSRC;

    __shared__ u16 Ks[64 * 64];
    __shared__ u16 Vs[VROWS * 64];
    __shared__ alignas(16) u16 pbuf[4][16 * 76];   // [i][j], stride 76 breaks conflicts

    short8 qf[2];
    #pragma unroll
    for (int kc = 0; kc < 2; ++kc)
        qf[kc] = ldfrag(qb + (size_t)(i0 + wave * 16) * HD + kc * 32, HD, lane);

    f32x4 o[5] = {};
    for (int jt = 0; jt < 16; ++jt) {
        int j0 = split * (NSRC / 4) + jt * 64;
        stage_tile<64>(Ks, kb + (size_t)j0 * HD, HD, t);
        stage_tile<VROWS>(Vs, vb + j0, NSRC, t);
        __syncthreads();
        // swapped QK^T: S^T tile, lane holds 4 consecutive j at fixed i=lane&15
        f32x4 s[4] = {};
        #pragma unroll
        for (int kc = 0; kc < 2; ++kc)
            #pragma unroll
            for (int jf = 0; jf < 4; ++jf)
                s[jf] = mfma16(rdfrag(Ks, jf * 16, kc * 4, lane), qf[kc], s[jf]);
        // P̃ = exp2(S): pack 4 bf16 (consecutive j) -> one b64 LDS write
        #pragma unroll
        for (int jf = 0; jf < 4; ++jf) {
            uint2 w;
            w.x = pk_bf16(fast_exp2(s[jf][0]), fast_exp2(s[jf][1]));
            w.y = pk_bf16(fast_exp2(s[jf][2]), fast_exp2(s[jf][3]));
            *(uint2*)&pbuf[wave][(size_t)(lane & 15) * 76 + jf * 16 + (lane >> 4) * 4] = w;
        }
        // PV: A = P̃ rows i, B = Vext rows d (df=4 row 64 -> rowsum)
        #pragma unroll
        for (int jc = 0; jc < 2; ++jc) {
            short8 pa = *(const short8*)&pbuf[wave][(size_t)(lane & 15) * 76 + jc * 32 + (lane >> 4) * 8];
            #pragma unroll
            for (int df = 0; df < 5; ++df)
                o[df] = mfma16(pa, rdfrag(Vs, df * 16, jc * 4, lane), o[df]);
        }
        __syncthreads();   // before next jt overwrites Ks/Vs
    }
    // rowsum = o[4] at col d=64 (lanes with lane&15==0)
    if ((lane & 15) == 0) {
        #pragma unroll
        for (int r = 0; r < 4; ++r)
            rs[((size_t)split * (BATCH * NH) + bh) * NSINK + i0 + wave * 16 + (lane >> 4) * 4 + r] = o[4][r];
    }
    int b = bh >> 3, h = bh & 7;
    float* pvp = pv + (size_t)split * BATCH * NSINK * DIM;
    #pragma unroll
    for (int df = 0; df < 4; ++df)
        #pragma unroll
        for (int r = 0; r < 4; ++r) {
            int row = i0 + wave * 16 + (lane >> 4) * 4 + r;
            pvp[((size_t)(b * NSINK + row)) * DIM + h * HD + df * 16 + (lane & 15)] = o[df][r];
        }
}

// ---------------- finalize: a = (sum pv + eps*vsum)/(sum rs + Neps) -> bf16 ----------------
__global__ __launch_bounds__(256) void finalize_pv(const float* __restrict__ pv,
    const float* __restrict__ rs, const float* __restrict__ vs,
    u16* __restrict__ ab)
{
    const int M = BATCH * NSINK * DIM;
    const int R = BATCH * NH * NSINK;
    int idx = blockIdx.x * 256 + threadIdx.x;
    int m = idx >> 9, n = idx & 511;
    int b = m >> 10, i = m & 1023, h = n >> 6, d = n & 63;
    int bh = b * NH + h;
    float val = pv[idx] + pv[idx + M] + pv[idx + 2 * M] + pv[idx + 3 * M]
              + EPS * vs[bh * HD + d];
    float rsv = rs[bh * NSINK + i] + rs[R + bh * NSINK + i]
              + rs[2 * R + bh * NSINK + i] + rs[3 * R + bh * NSINK + i]
              + (float)NSRC * EPS;
    ab[idx] = f2bf(val / rsv);
}

extern "C" void kernel_launch(void* const* d_in, const int* in_sizes, int n_in,
                              void* d_out, int out_size, void* d_ws, size_t ws_size,
                              hipStream_t stream) {
    (void)in_sizes; (void)n_in; (void)out_size;
    const float* sink    = (const float*)d_in[0];
    const float* source  = (const float*)d_in[1];
    const float* gamma_s = (const float*)d_in[2];
    const float* beta_s  = (const float*)d_in[3];
    const float* gamma_c = (const float*)d_in[4];
    const float* beta_c  = (const float*)d_in[5];
    const float* Wq      = (const float*)d_in[6];
    const float* bq      = (const float*)d_in[7];
    const float* Wkv     = (const float*)d_in[8];
    const float* bkv     = (const float*)d_in[9];
    const float* Wo      = (const float*)d_in[10];
    const float* bo      = (const float*)d_in[11];
    float* out = (float*)d_out;

    char* p = (char*)d_ws;
    auto carve = [&](size_t bytes) { char* r = p; p += (bytes + 255) & ~(size_t)255; return r; };
    u16* sh    = (u16*)carve(2048ull * 512 * 2);       // LN'd sink
    u16* ch    = (u16*)carve(8192ull * 512 * 2);       // LN'd source
    u16* wqT   = (u16*)carve(512ull * 512 * 2);
    u16* wkvT  = (u16*)carve(1024ull * 512 * 2);
    u16* woT   = (u16*)carve(512ull * 512 * 2);
    u16* qb    = (u16*)carve(16ull * 1024 * 64 * 2);
    u16* kb    = (u16*)carve(16ull * 4096 * 64 * 2);
    u16* vTh   = (u16*)carve(16ull * 64 * 4096 * 2);
    u16* vT2   = (u16*)carve(16ull * VROWS * 4096 * 2);
    float* colsum  = (float*)carve(16ull * 4096 * 4);
    float* cs_part = (float*)carve(4ull * 16 * 4096 * 4);
    float* vs      = (float*)carve(1024ull * 4);
    float* rs      = (float*)carve(4ull * 16 * 1024 * 4);
    float* pv      = (float*)carve(4ull * 2048 * 512 * 4);
    u16*   ab      = (u16*)carve(2048ull * 512 * 2);
    if ((size_t)(p - (char*)d_ws) > ws_size) return;

    ln_bf16<<<BATCH * NSINK, 256, 0, stream>>>(sink, gamma_s, beta_s, sh);
    ln_bf16<<<BATCH * NSRC,  256, 0, stream>>>(source, gamma_c, beta_c, ch);
    wt_t<<<512,  256, 0, stream>>>(Wq, 512, 512, wqT);
    wt_t<<<1024, 256, 0, stream>>>(Wkv, 512, 1024, wkvT);
    wt_t<<<512,  256, 0, stream>>>(Wo, 512, 512, woT);

    gemm1<1, 64, 64><<<dim3(DIM / 64, BATCH * NSINK / 64), 256, 0, stream>>>(
        sh, wqT, bq, 512, nullptr, qb, nullptr);
    gemm1<2, 128, 128><<<dim3(2 * DIM / 128, BATCH * NSRC / 128), 256, 0, stream>>>(
        ch, wkvT, bkv, 512, nullptr, kb, vTh);

    vsum_k<<<1024, 256, 0, stream>>>(vTh, vs);
    pass_a<<<1024, 256, 0, stream>>>(qb, kb, cs_part);
    csum_red<<<BATCH * NH * NSRC / 256, 256, 0, stream>>>(cs_part, colsum);
    vscale<<<dim3(VROWS, BATCH * NH), 256, 0, stream>>>(vTh, colsum, vT2);
    pass_b<<<1024, 256, 0, stream>>>(qb, kb, vT2, pv, rs);
    finalize_pv<<<4096, 256, 0, stream>>>(pv, rs, vs, ab);

    gemm1<0, 64, 64><<<dim3(DIM / 64, BATCH * NSINK / 64), 256, 0, stream>>>(
        ab, woT, bo, 512, out, nullptr, nullptr);
}

// Round 9
// 135.478 us; speedup vs baseline: 1.9772x; 1.0555x over previous
//
#include <hip/hip_runtime.h>
#include <hip/hip_bf16.h>
#include <math.h>

#define EPS 1e-6f
#define NSINK 1024
#define NSRC 4096
#define DIM 512
#define NH 8
#define HD 64
#define BATCH 2
#define VROWS 65   // extended V: 0..63 = v/cs, 64 = 1/cs
// fold (d^-0.5 = 1/8) * log2(e) into q so sim exp is a single exp2
#define QSCALE 0.18033688011112042f

typedef unsigned short u16;
typedef __attribute__((ext_vector_type(8))) short short8;
typedef __attribute__((ext_vector_type(4))) float f32x4;

__device__ inline float fast_exp2(float x) {
#if __has_builtin(__builtin_amdgcn_exp2f)
    return __builtin_amdgcn_exp2f(x);
#else
    return exp2f(x);
#endif
}
__device__ inline float fast_rcp(float x) {
#if __has_builtin(__builtin_amdgcn_rcpf)
    return __builtin_amdgcn_rcpf(x);
#else
    return 1.0f / x;
#endif
}
__device__ inline u16 f2bf(float x) {
    union { float f; unsigned u; } v; v.f = x;
    unsigned r = v.u + 0x7fffu + ((v.u >> 16) & 1u);
    return (u16)(r >> 16);
}
__device__ inline float bf2f(u16 h) {
    union { unsigned u; float f; } v; v.u = ((unsigned)h) << 16;
    return v.f;
}
// pack 2 f32 -> 2 bf16 (RTNE) in one u32; lowers to v_cvt_pk_bf16_f32
__device__ inline unsigned pk_bf16(float a, float b) {
    union { __hip_bfloat162 h; unsigned u; } v;
    v.h = __float22bfloat162_rn(make_float2(a, b));
    return v.u;
}
__device__ inline f32x4 mfma16(short8 a, short8 b, f32x4 c) {
    return __builtin_amdgcn_mfma_f32_16x16x32_bf16(a, b, c, 0, 0, 0);
}
// direct-from-global fragment loader
__device__ inline short8 ldfrag(const u16* base, int stride, int lane) {
    return *(const short8*)(base + (size_t)(lane & 15) * stride + ((lane >> 4) << 3));
}

// async global->LDS, 16B per lane
__device__ inline void gld16(const u16* g, u16* l) {
    __builtin_amdgcn_global_load_lds(
        (const __attribute__((address_space(1))) unsigned*)g,
        (__attribute__((address_space(3))) unsigned*)l, 16, 0, 0);
}

// stage a [TM][64] bf16 tile from gsrc (row-major, stride K);
// LDS linear dest; global source inverse-swizzled (c ^= m&7).
template<int TM>
__device__ inline void stage_tile(u16* lds, const u16* gsrc, int K, int t) {
    #pragma unroll
    for (int it = 0; it < TM / 32; ++it) {
        int m = it * 32 + (t >> 3);
        int c = (t & 7) ^ (m & 7);
        gld16(gsrc + (size_t)m * K + c * 8,
              lds + it * 2048 + (t >> 6) * 512);
    }
}
// swizzled fragment read
__device__ inline short8 rdfrag(const u16* tile, int fbase, int cbase, int lane) {
    int m = fbase + (lane & 15);
    int c = (cbase + (lane >> 4)) ^ (m & 7);
    return *(const short8*)(tile + (size_t)m * 64 + c * 8);
}

// ---------------- fused LayerNorm (both inputs) -> bf16 ----------------
__global__ __launch_bounds__(256) void ln_all(
    const float* __restrict__ sink, const float* __restrict__ source,
    const float* __restrict__ gs, const float* __restrict__ bs,
    const float* __restrict__ gc, const float* __restrict__ bc,
    u16* __restrict__ sh, u16* __restrict__ ch)
{
    int row = blockIdx.x;
    const float* xr; const float* g; const float* be; u16* y;
    if (row < BATCH * NSINK) {
        xr = sink + (size_t)row * DIM; g = gs; be = bs; y = sh + (size_t)row * DIM;
    } else {
        int rr = row - BATCH * NSINK;
        xr = source + (size_t)rr * DIM; g = gc; be = bc; y = ch + (size_t)rr * DIM;
    }
    int t = threadIdx.x;
    float v0 = xr[t], v1 = xr[t + 256];
    float s = v0 + v1, sq = v0 * v0 + v1 * v1;
    #pragma unroll
    for (int off = 32; off > 0; off >>= 1) {
        s  += __shfl_down(s, off, 64);
        sq += __shfl_down(sq, off, 64);
    }
    __shared__ float rsm[4], rq[4];
    int wave = t >> 6;
    if ((t & 63) == 0) { rsm[wave] = s; rq[wave] = sq; }
    __syncthreads();
    s  = rsm[0] + rsm[1] + rsm[2] + rsm[3];
    sq = rq[0] + rq[1] + rq[2] + rq[3];
    float mu = s * (1.0f / DIM);
    float var = sq * (1.0f / DIM) - mu * mu;
    float a = var + EPS;
    float r = rsqrtf(a);
    r = r * (1.5f - 0.5f * a * r * r);
    y[t]       = f2bf((v0 - mu) * r * g[t] + be[t]);
    y[t + 256] = f2bf((v1 - mu) * r * g[t + 256] + be[t + 256]);
}

// ---------------- fused weight transpose: all three W[K][N] -> T[N][K] bf16 ----------------
__global__ __launch_bounds__(256) void wt_all(
    const float* __restrict__ Wq, const float* __restrict__ Wkv, const float* __restrict__ Wo,
    u16* __restrict__ wqT, u16* __restrict__ wkvT, u16* __restrict__ woT)
{
    int n = blockIdx.x;   // 0..2047
    const float* W; u16* T; int N; int nn;
    if (n < 512)       { W = Wq;  T = wqT;  N = 512;  nn = n; }
    else if (n < 1536) { W = Wkv; T = wkvT; N = 1024; nn = n - 512; }
    else               { W = Wo;  T = woT;  N = 512;  nn = n - 1536; }
    for (int k = threadIdx.x; k < 512; k += 256)
        T[(size_t)nn * 512 + k] = f2bf(W[(size_t)k * N + nn]);
}

// ---------------- 1-term 2-phase LDS-dbuf MFMA GEMM: C = A @ BT^T + bias ----------------
// MODE 0: C fp32 row-major. MODE 1: q bf16 [bh][i][d] * QSCALE.
// MODE 2: n<512 -> k bf16 [bh][j][d]; n>=512 -> vT bf16 [bh*64+d][j].
template<int MODE, int TM, int TN>
__global__ __launch_bounds__(256) void gemm1(
    const u16* __restrict__ A, const u16* __restrict__ BT,
    const float* __restrict__ bias, int K,
    float* __restrict__ cf, u16* __restrict__ o1, u16* __restrict__ o2)
{
    constexpr int FM = TM / 32, FN = TN / 32;
    __shared__ u16 As[2][TM * 64];
    __shared__ u16 Bs[2][TN * 64];
    int t = threadIdx.x;
    int wave = t >> 6, lane = t & 63;
    int wr = wave >> 1, wc = wave & 1;
    int m0 = blockIdx.y * TM, n0 = blockIdx.x * TN;

    f32x4 acc[FM][FN] = {};
    stage_tile<TM>(As[0], A + (size_t)m0 * K, K, t);
    stage_tile<TN>(Bs[0], BT + (size_t)n0 * K, K, t);
    __syncthreads();
    int nt = K >> 6;
    int cur = 0;
    for (int kt = 0; kt < nt; ++kt) {
        if (kt + 1 < nt) {
            stage_tile<TM>(As[cur ^ 1], A + (size_t)m0 * K + (kt + 1) * 64, K, t);
            stage_tile<TN>(Bs[cur ^ 1], BT + (size_t)n0 * K + (kt + 1) * 64, K, t);
        }
        #pragma unroll
        for (int kk = 0; kk < 2; ++kk) {
            short8 af[FM], bf[FN];
            #pragma unroll
            for (int f = 0; f < FM; ++f)
                af[f] = rdfrag(As[cur], wr * (TM / 2) + f * 16, kk * 4, lane);
            #pragma unroll
            for (int f = 0; f < FN; ++f)
                bf[f] = rdfrag(Bs[cur], wc * (TN / 2) + f * 16, kk * 4, lane);
            #pragma unroll
            for (int i = 0; i < FM; ++i)
                #pragma unroll
                for (int j = 0; j < FN; ++j)
                    acc[i][j] = mfma16(af[i], bf[j], acc[i][j]);
        }
        __syncthreads();
        cur ^= 1;
    }

    #pragma unroll
    for (int i = 0; i < FM; ++i)
        #pragma unroll
        for (int j = 0; j < FN; ++j)
            #pragma unroll
            for (int r = 0; r < 4; ++r) {
                int m = m0 + wr * (TM / 2) + i * 16 + (lane >> 4) * 4 + r;
                int n = n0 + wc * (TN / 2) + j * 16 + (lane & 15);
                float v = acc[i][j][r] + bias[n];
                if (MODE == 0) {
                    cf[(size_t)m * DIM + n] = v;
                } else if (MODE == 1) {
                    int b = m >> 10, ii = m & 1023;
                    int h = n >> 6, d = n & 63;
                    o1[((size_t)(b * NH + h) * NSINK + ii) * HD + d] = f2bf(v * QSCALE);
                } else {
                    int b = m >> 12, jj = m & 4095;
                    if (n < DIM) {
                        int h = n >> 6, d = n & 63;
                        o1[((size_t)(b * NH + h) * NSRC + jj) * HD + d] = f2bf(v);
                    } else {
                        int nn = n - DIM;
                        int h = nn >> 6, d = nn & 63;
                        o2[((size_t)(b * NH + h) * HD + d) * NSRC + jj] = f2bf(v);
                    }
                }
            }
}

// ---------------- pass A: colsum_part[ic][bh][j] = sum_{i chunk} exp2(q.k) ----------------
__global__ __launch_bounds__(256, 4) void pass_a(const u16* __restrict__ q,
    const u16* __restrict__ k, float* __restrict__ part)
{
    int id = blockIdx.x;
    int slot = id >> 3;
    int bh = (id & 7) + 8 * (slot >> 6);
    int rem = slot & 63;
    int ic = rem >> 4;
    int wave = threadIdx.x >> 6, lane = threadIdx.x & 63;
    int j0 = (rem & 15) * 256 + wave * 64;
    const u16* qb = q + (size_t)bh * NSINK * HD;
    const u16* kb = k + (size_t)bh * NSRC * HD;
    short8 kf[4][2];
    #pragma unroll
    for (int jf = 0; jf < 4; ++jf)
        #pragma unroll
        for (int kc = 0; kc < 2; ++kc)
            kf[jf][kc] = ldfrag(kb + (size_t)(j0 + jf * 16) * HD + kc * 32, HD, lane);
    float csum[4] = {};
    for (int ii = 0; ii < 4; ++ii) {
        int ibase = ic * 256 + ii * 64;
        #pragma unroll
        for (int f = 0; f < 4; ++f) {
            short8 q0 = ldfrag(qb + (size_t)(ibase + f * 16) * HD, HD, lane);
            short8 q1 = ldfrag(qb + (size_t)(ibase + f * 16) * HD + 32, HD, lane);
            f32x4 s[4] = {};
            #pragma unroll
            for (int jf = 0; jf < 4; ++jf) s[jf] = mfma16(q0, kf[jf][0], s[jf]);
            #pragma unroll
            for (int jf = 0; jf < 4; ++jf) s[jf] = mfma16(q1, kf[jf][1], s[jf]);
            #pragma unroll
            for (int jf = 0; jf < 4; ++jf)
                csum[jf] += fast_exp2(s[jf][0]) + fast_exp2(s[jf][1])
                          + fast_exp2(s[jf][2]) + fast_exp2(s[jf][3]);
        }
    }
    #pragma unroll
    for (int jf = 0; jf < 4; ++jf) {
        csum[jf] += __shfl_xor(csum[jf], 16, 64);
        csum[jf] += __shfl_xor(csum[jf], 32, 64);
    }
    if (lane < 16)
        #pragma unroll
        for (int jf = 0; jf < 4; ++jf)
            part[((size_t)ic * BATCH * NH + bh) * NSRC + j0 + jf * 16 + lane] = csum[jf];
}

// ---------------- vscale2: fused csum-reduce + v/cs + 1/cs row + vsum ----------------
// grid (VROWS, 16): d<64: vT2=v/cs & vs=sum(v); d==64: vT2=1/cs
__global__ __launch_bounds__(256) void vscale2(const u16* __restrict__ vTh,
    const float* __restrict__ cs_part, float* __restrict__ vs, u16* __restrict__ vT2)
{
    int d = blockIdx.x;   // 0..64
    int bh = blockIdx.y;  // 0..15
    const int S = BATCH * NH * NSRC;
    const float* cp = cs_part + (size_t)bh * NSRC;
    u16* dst = vT2 + ((size_t)bh * VROWS + d) * NSRC;
    if (d == 64) {
        for (int j = threadIdx.x; j < NSRC; j += 256) {
            float cs = cp[j] + cp[j + S] + cp[j + 2 * S] + cp[j + 3 * S];
            dst[j] = f2bf(fast_rcp(cs));
        }
        return;
    }
    const u16* src = vTh + ((size_t)bh * HD + d) * NSRC;
    float acc = 0.f;
    for (int j = threadIdx.x; j < NSRC; j += 256) {
        float v = bf2f(src[j]);
        acc += v;
        float cs = cp[j] + cp[j + S] + cp[j + 2 * S] + cp[j + 3 * S];
        dst[j] = f2bf(v * fast_rcp(cs));
    }
    #pragma unroll
    for (int off = 32; off > 0; off >>= 1) acc += __shfl_down(acc, off, 64);
    __shared__ float r4[4];
    if ((threadIdx.x & 63) == 0) r4[threadIdx.x >> 6] = acc;
    __syncthreads();
    if (threadIdx.x == 0) vs[bh * HD + d] = r4[0] + r4[1] + r4[2] + r4[3];
}

// ---------------- pass B: dbuf-staged; P = exp2(KQ^T) bf16; O = P·Vext ----------------
// 1-D grid 1024: id%8==bh%8; waves split i (16 rows each); j-quarter loop
__global__ __launch_bounds__(256, 3) void pass_b(const u16* __restrict__ q,
    const u16* __restrict__ k, const u16* __restrict__ vT2,
    float* __restrict__ pv, float* __restrict__ rs)
{
    int id = blockIdx.x;
    int slot = id >> 3;
    int bh = (id & 7) + 8 * (slot >> 6);
    int rem = slot & 63;
    int split = rem >> 4;        // 0..3
    int i0 = (rem & 15) * 64;    // 0..960
    int t = threadIdx.x, wave = t >> 6, lane = t & 63;
    const u16* qb = q + (size_t)bh * NSINK * HD;
    const u16* kb = k + (size_t)bh * NSRC * HD;
    const u16* vb = vT2 + (size_t)bh * VROWS * NSRC;

    __shared__ u16 Ks[2][64 * 64];
    __shared__ u16 Vs[2][64 * 64];
    __shared__ alignas(16) u16 Rcs[2][64];
    __shared__ alignas(16) u16 pbuf[4][16 * 76];   // [i][j], stride 76 breaks conflicts

    short8 qf[2];
    #pragma unroll
    for (int kc = 0; kc < 2; ++kc)
        qf[kc] = ldfrag(qb + (size_t)(i0 + wave * 16) * HD + kc * 32, HD, lane);

    auto stage = [&](int buf, int jt) {
        int j0 = split * (NSRC / 4) + jt * 64;
        stage_tile<64>(Ks[buf], kb + (size_t)j0 * HD, HD, t);
        stage_tile<64>(Vs[buf], vb + j0, NSRC, t);
        if (t < 8) gld16(vb + (size_t)64 * NSRC + j0 + t * 8, Rcs[buf]);
    };

    f32x4 o[5] = {};
    stage(0, 0);
    __syncthreads();
    int cur = 0;
    for (int jt = 0; jt < 16; ++jt) {
        if (jt + 1 < 16) stage(cur ^ 1, jt + 1);   // prefetch overlaps compute
        // swapped QK^T: S^T tile, lane holds 4 consecutive j at fixed i=lane&15
        f32x4 s[4] = {};
        #pragma unroll
        for (int kc = 0; kc < 2; ++kc)
            #pragma unroll
            for (int jf = 0; jf < 4; ++jf)
                s[jf] = mfma16(rdfrag(Ks[cur], jf * 16, kc * 4, lane), qf[kc], s[jf]);
        // P̃ = exp2(S): pack 4 bf16 (consecutive j) -> one b64 LDS write
        #pragma unroll
        for (int jf = 0; jf < 4; ++jf) {
            uint2 w;
            w.x = pk_bf16(fast_exp2(s[jf][0]), fast_exp2(s[jf][1]));
            w.y = pk_bf16(fast_exp2(s[jf][2]), fast_exp2(s[jf][3]));
            *(uint2*)&pbuf[wave][(size_t)(lane & 15) * 76 + jf * 16 + (lane >> 4) * 4] = w;
        }
        // PV: A = P̃ rows i; B = V/cs rows (df<4) + in-register 1/cs fragment (rowsum)
        short8 z = {};
        #pragma unroll
        for (int jc = 0; jc < 2; ++jc) {
            short8 pa = *(const short8*)&pbuf[wave][(size_t)(lane & 15) * 76 + jc * 32 + (lane >> 4) * 8];
            #pragma unroll
            for (int df = 0; df < 4; ++df)
                o[df] = mfma16(pa, rdfrag(Vs[cur], df * 16, jc * 4, lane), o[df]);
            short8 b5 = z;
            if ((lane & 15) == 0)
                b5 = *(const short8*)&Rcs[cur][jc * 32 + (lane >> 4) * 8];
            o[4] = mfma16(pa, b5, o[4]);
        }
        __syncthreads();   // drains prefetch vmcnt; guards buffer reuse
        cur ^= 1;
    }
    // rowsum = o[4] col 0 (lanes with lane&15==0)
    if ((lane & 15) == 0) {
        #pragma unroll
        for (int r = 0; r < 4; ++r)
            rs[((size_t)split * (BATCH * NH) + bh) * NSINK + i0 + wave * 16 + (lane >> 4) * 4 + r] = o[4][r];
    }
    int b = bh >> 3, h = bh & 7;
    float* pvp = pv + (size_t)split * BATCH * NSINK * DIM;
    #pragma unroll
    for (int df = 0; df < 4; ++df)
        #pragma unroll
        for (int r = 0; r < 4; ++r) {
            int row = i0 + wave * 16 + (lane >> 4) * 4 + r;
            pvp[((size_t)(b * NSINK + row)) * DIM + h * HD + df * 16 + (lane & 15)] = o[df][r];
        }
}

// ---------------- finalize: a = (sum pv + eps*vsum)/(sum rs + Neps) -> bf16 ----------------
__global__ __launch_bounds__(256) void finalize_pv(const float* __restrict__ pv,
    const float* __restrict__ rs, const float* __restrict__ vs,
    u16* __restrict__ ab)
{
    const int M = BATCH * NSINK * DIM;
    const int R = BATCH * NH * NSINK;
    int idx = blockIdx.x * 256 + threadIdx.x;
    int m = idx >> 9, n = idx & 511;
    int b = m >> 10, i = m & 1023, h = n >> 6, d = n & 63;
    int bh = b * NH + h;
    float val = pv[idx] + pv[idx + M] + pv[idx + 2 * M] + pv[idx + 3 * M]
              + EPS * vs[bh * HD + d];
    float rsv = rs[bh * NSINK + i] + rs[R + bh * NSINK + i]
              + rs[2 * R + bh * NSINK + i] + rs[3 * R + bh * NSINK + i]
              + (float)NSRC * EPS;
    ab[idx] = f2bf(val / rsv);
}

extern "C" void kernel_launch(void* const* d_in, const int* in_sizes, int n_in,
                              void* d_out, int out_size, void* d_ws, size_t ws_size,
                              hipStream_t stream) {
    (void)in_sizes; (void)n_in; (void)out_size;
    const float* sink    = (const float*)d_in[0];
    const float* source  = (const float*)d_in[1];
    const float* gamma_s = (const float*)d_in[2];
    const float* beta_s  = (const float*)d_in[3];
    const float* gamma_c = (const float*)d_in[4];
    const float* beta_c  = (const float*)d_in[5];
    const float* Wq      = (const float*)d_in[6];
    const float* bq      = (const float*)d_in[7];
    const float* Wkv     = (const float*)d_in[8];
    const float* bkv     = (const float*)d_in[9];
    const float* Wo      = (const float*)d_in[10];
    const float* bo      = (const float*)d_in[11];
    float* out = (float*)d_out;

    char* p = (char*)d_ws;
    auto carve = [&](size_t bytes) { char* r = p; p += (bytes + 255) & ~(size_t)255; return r; };
    u16* sh    = (u16*)carve(2048ull * 512 * 2);       // LN'd sink
    u16* ch    = (u16*)carve(8192ull * 512 * 2);       // LN'd source
    u16* wqT   = (u16*)carve(512ull * 512 * 2);
    u16* wkvT  = (u16*)carve(1024ull * 512 * 2);
    u16* woT   = (u16*)carve(512ull * 512 * 2);
    u16* qb    = (u16*)carve(16ull * 1024 * 64 * 2);
    u16* kb    = (u16*)carve(16ull * 4096 * 64 * 2);
    u16* vTh   = (u16*)carve(16ull * 64 * 4096 * 2);
    u16* vT2   = (u16*)carve(16ull * VROWS * 4096 * 2);
    float* cs_part = (float*)carve(4ull * 16 * 4096 * 4);
    float* vs      = (float*)carve(1024ull * 4);
    float* rs      = (float*)carve(4ull * 16 * 1024 * 4);
    float* pv      = (float*)carve(4ull * 2048 * 512 * 4);
    u16*   ab      = (u16*)carve(2048ull * 512 * 2);
    if ((size_t)(p - (char*)d_ws) > ws_size) return;

    ln_all<<<BATCH * (NSINK + NSRC), 256, 0, stream>>>(
        sink, source, gamma_s, beta_s, gamma_c, beta_c, sh, ch);
    wt_all<<<2048, 256, 0, stream>>>(Wq, Wkv, Wo, wqT, wkvT, woT);

    gemm1<1, 64, 64><<<dim3(DIM / 64, BATCH * NSINK / 64), 256, 0, stream>>>(
        sh, wqT, bq, 512, nullptr, qb, nullptr);
    gemm1<2, 128, 128><<<dim3(2 * DIM / 128, BATCH * NSRC / 128), 256, 0, stream>>>(
        ch, wkvT, bkv, 512, nullptr, kb, vTh);

    pass_a<<<1024, 256, 0, stream>>>(qb, kb, cs_part);
    vscale2<<<dim3(VROWS, BATCH * NH), 256, 0, stream>>>(vTh, cs_part, vs, vT2);
    pass_b<<<1024, 256, 0, stream>>>(qb, kb, vT2, pv, rs);
    finalize_pv<<<4096, 256, 0, stream>>>(pv, rs, vs, ab);

    gemm1<0, 64, 64><<<dim3(DIM / 64, BATCH * NSINK / 64), 256, 0, stream>>>(
        ab, woT, bo, 512, out, nullptr, nullptr);
}

// Round 10
// 127.157 us; speedup vs baseline: 2.1066x; 1.0654x over previous
//
#include <hip/hip_runtime.h>
#include <hip/hip_bf16.h>
#include <math.h>

#define EPS 1e-6f
#define NSINK 1024
#define NSRC 4096
#define DIM 512
#define NH 8
#define HD 64
#define BATCH 2
#define VROWS 65   // extended V: 0..63 = v/cs, 64 = 1/cs
// fold (d^-0.5 = 1/8) * log2(e) into q so sim exp is a single exp2
#define QSCALE 0.18033688011112042f

typedef unsigned short u16;
typedef __attribute__((ext_vector_type(8))) short short8;
typedef __attribute__((ext_vector_type(4))) float f32x4;

__device__ inline float fast_exp2(float x) {
#if __has_builtin(__builtin_amdgcn_exp2f)
    return __builtin_amdgcn_exp2f(x);
#else
    return exp2f(x);
#endif
}
__device__ inline float fast_rcp(float x) {
#if __has_builtin(__builtin_amdgcn_rcpf)
    return __builtin_amdgcn_rcpf(x);
#else
    return 1.0f / x;
#endif
}
__device__ inline u16 f2bf(float x) {
    union { float f; unsigned u; } v; v.f = x;
    unsigned r = v.u + 0x7fffu + ((v.u >> 16) & 1u);
    return (u16)(r >> 16);
}
__device__ inline float bf2f(u16 h) {
    union { unsigned u; float f; } v; v.u = ((unsigned)h) << 16;
    return v.f;
}
// pack 2 f32 -> 2 bf16 (RTNE) in one u32; lowers to v_cvt_pk_bf16_f32
__device__ inline unsigned pk_bf16(float a, float b) {
    union { __hip_bfloat162 h; unsigned u; } v;
    v.h = __float22bfloat162_rn(make_float2(a, b));
    return v.u;
}
__device__ inline f32x4 mfma16(short8 a, short8 b, f32x4 c) {
    return __builtin_amdgcn_mfma_f32_16x16x32_bf16(a, b, c, 0, 0, 0);
}
// direct-from-global fragment loader
__device__ inline short8 ldfrag(const u16* base, int stride, int lane) {
    return *(const short8*)(base + (size_t)(lane & 15) * stride + ((lane >> 4) << 3));
}

// async global->LDS, 16B per lane
__device__ inline void gld16(const u16* g, u16* l) {
    __builtin_amdgcn_global_load_lds(
        (const __attribute__((address_space(1))) unsigned*)g,
        (__attribute__((address_space(3))) unsigned*)l, 16, 0, 0);
}

// stage a [TM][64] bf16 tile from gsrc (row-major, stride K);
// LDS linear dest; global source inverse-swizzled (c ^= m&7).
template<int TM>
__device__ inline void stage_tile(u16* lds, const u16* gsrc, int K, int t) {
    #pragma unroll
    for (int it = 0; it < TM / 32; ++it) {
        int m = it * 32 + (t >> 3);
        int c = (t & 7) ^ (m & 7);
        gld16(gsrc + (size_t)m * K + c * 8,
              lds + it * 2048 + (t >> 6) * 512);
    }
}
// swizzled fragment read
__device__ inline short8 rdfrag(const u16* tile, int fbase, int cbase, int lane) {
    int m = fbase + (lane & 15);
    int c = (cbase + (lane >> 4)) ^ (m & 7);
    return *(const short8*)(tile + (size_t)m * 64 + c * 8);
}

// ---------------- fused LayerNorm (both inputs) -> bf16 ----------------
__global__ __launch_bounds__(256) void ln_all(
    const float* __restrict__ sink, const float* __restrict__ source,
    const float* __restrict__ gs, const float* __restrict__ bs,
    const float* __restrict__ gc, const float* __restrict__ bc,
    u16* __restrict__ sh, u16* __restrict__ ch)
{
    int row = blockIdx.x;
    const float* xr; const float* g; const float* be; u16* y;
    if (row < BATCH * NSINK) {
        xr = sink + (size_t)row * DIM; g = gs; be = bs; y = sh + (size_t)row * DIM;
    } else {
        int rr = row - BATCH * NSINK;
        xr = source + (size_t)rr * DIM; g = gc; be = bc; y = ch + (size_t)rr * DIM;
    }
    int t = threadIdx.x;
    float v0 = xr[t], v1 = xr[t + 256];
    float s = v0 + v1, sq = v0 * v0 + v1 * v1;
    #pragma unroll
    for (int off = 32; off > 0; off >>= 1) {
        s  += __shfl_down(s, off, 64);
        sq += __shfl_down(sq, off, 64);
    }
    __shared__ float rsm[4], rq[4];
    int wave = t >> 6;
    if ((t & 63) == 0) { rsm[wave] = s; rq[wave] = sq; }
    __syncthreads();
    s  = rsm[0] + rsm[1] + rsm[2] + rsm[3];
    sq = rq[0] + rq[1] + rq[2] + rq[3];
    float mu = s * (1.0f / DIM);
    float var = sq * (1.0f / DIM) - mu * mu;
    float a = var + EPS;
    float r = rsqrtf(a);
    r = r * (1.5f - 0.5f * a * r * r);
    y[t]       = f2bf((v0 - mu) * r * g[t] + be[t]);
    y[t + 256] = f2bf((v1 - mu) * r * g[t + 256] + be[t + 256]);
}

// ---------------- fused weight transpose: all three W[K][N] -> T[N][K] bf16 ----------------
__global__ __launch_bounds__(256) void wt_all(
    const float* __restrict__ Wq, const float* __restrict__ Wkv, const float* __restrict__ Wo,
    u16* __restrict__ wqT, u16* __restrict__ wkvT, u16* __restrict__ woT)
{
    int n = blockIdx.x;   // 0..2047
    const float* W; u16* T; int N; int nn;
    if (n < 512)       { W = Wq;  T = wqT;  N = 512;  nn = n; }
    else if (n < 1536) { W = Wkv; T = wkvT; N = 1024; nn = n - 512; }
    else               { W = Wo;  T = woT;  N = 512;  nn = n - 1536; }
    for (int k = threadIdx.x; k < 512; k += 256)
        T[(size_t)nn * 512 + k] = f2bf(W[(size_t)k * N + nn]);
}

// ---------------- 1-term 2-phase LDS-dbuf MFMA GEMM: C = A @ BT^T + bias ----------------
// MODE 0: C fp32 row-major. MODE 1: q bf16 [bh][i][d] * QSCALE.
// MODE 2: n<512 -> k bf16 [bh][j][d]; n>=512 -> vT bf16 [bh*64+d][j].
template<int MODE, int TM, int TN>
__global__ __launch_bounds__(256) void gemm1(
    const u16* __restrict__ A, const u16* __restrict__ BT,
    const float* __restrict__ bias, int K,
    float* __restrict__ cf, u16* __restrict__ o1, u16* __restrict__ o2)
{
    constexpr int FM = TM / 32, FN = TN / 32;
    __shared__ u16 As[2][TM * 64];
    __shared__ u16 Bs[2][TN * 64];
    int t = threadIdx.x;
    int wave = t >> 6, lane = t & 63;
    int wr = wave >> 1, wc = wave & 1;
    int m0 = blockIdx.y * TM, n0 = blockIdx.x * TN;

    f32x4 acc[FM][FN] = {};
    stage_tile<TM>(As[0], A + (size_t)m0 * K, K, t);
    stage_tile<TN>(Bs[0], BT + (size_t)n0 * K, K, t);
    __syncthreads();
    int nt = K >> 6;
    int cur = 0;
    for (int kt = 0; kt < nt; ++kt) {
        if (kt + 1 < nt) {
            stage_tile<TM>(As[cur ^ 1], A + (size_t)m0 * K + (kt + 1) * 64, K, t);
            stage_tile<TN>(Bs[cur ^ 1], BT + (size_t)n0 * K + (kt + 1) * 64, K, t);
        }
        #pragma unroll
        for (int kk = 0; kk < 2; ++kk) {
            short8 af[FM], bf[FN];
            #pragma unroll
            for (int f = 0; f < FM; ++f)
                af[f] = rdfrag(As[cur], wr * (TM / 2) + f * 16, kk * 4, lane);
            #pragma unroll
            for (int f = 0; f < FN; ++f)
                bf[f] = rdfrag(Bs[cur], wc * (TN / 2) + f * 16, kk * 4, lane);
            #pragma unroll
            for (int i = 0; i < FM; ++i)
                #pragma unroll
                for (int j = 0; j < FN; ++j)
                    acc[i][j] = mfma16(af[i], bf[j], acc[i][j]);
        }
        __syncthreads();
        cur ^= 1;
    }

    #pragma unroll
    for (int i = 0; i < FM; ++i)
        #pragma unroll
        for (int j = 0; j < FN; ++j)
            #pragma unroll
            for (int r = 0; r < 4; ++r) {
                int m = m0 + wr * (TM / 2) + i * 16 + (lane >> 4) * 4 + r;
                int n = n0 + wc * (TN / 2) + j * 16 + (lane & 15);
                float v = acc[i][j][r] + bias[n];
                if (MODE == 0) {
                    cf[(size_t)m * DIM + n] = v;
                } else if (MODE == 1) {
                    int b = m >> 10, ii = m & 1023;
                    int h = n >> 6, d = n & 63;
                    o1[((size_t)(b * NH + h) * NSINK + ii) * HD + d] = f2bf(v * QSCALE);
                } else {
                    int b = m >> 12, jj = m & 4095;
                    if (n < DIM) {
                        int h = n >> 6, d = n & 63;
                        o1[((size_t)(b * NH + h) * NSRC + jj) * HD + d] = f2bf(v);
                    } else {
                        int nn = n - DIM;
                        int h = nn >> 6, d = nn & 63;
                        o2[((size_t)(b * NH + h) * HD + d) * NSRC + jj] = f2bf(v);
                    }
                }
            }
}

// ---------------- pass A: colsum_part[ic][bh][j] = sum_{i chunk} exp2(q.k) ----------------
__global__ __launch_bounds__(256, 4) void pass_a(const u16* __restrict__ q,
    const u16* __restrict__ k, float* __restrict__ part)
{
    int id = blockIdx.x;
    int slot = id >> 3;
    int bh = (id & 7) + 8 * (slot >> 6);
    int rem = slot & 63;
    int ic = rem >> 4;
    int wave = threadIdx.x >> 6, lane = threadIdx.x & 63;
    int j0 = (rem & 15) * 256 + wave * 64;
    const u16* qb = q + (size_t)bh * NSINK * HD;
    const u16* kb = k + (size_t)bh * NSRC * HD;
    short8 kf[4][2];
    #pragma unroll
    for (int jf = 0; jf < 4; ++jf)
        #pragma unroll
        for (int kc = 0; kc < 2; ++kc)
            kf[jf][kc] = ldfrag(kb + (size_t)(j0 + jf * 16) * HD + kc * 32, HD, lane);
    float csum[4] = {};
    for (int ii = 0; ii < 4; ++ii) {
        int ibase = ic * 256 + ii * 64;
        #pragma unroll
        for (int f = 0; f < 4; ++f) {
            short8 q0 = ldfrag(qb + (size_t)(ibase + f * 16) * HD, HD, lane);
            short8 q1 = ldfrag(qb + (size_t)(ibase + f * 16) * HD + 32, HD, lane);
            f32x4 s[4] = {};
            #pragma unroll
            for (int jf = 0; jf < 4; ++jf) s[jf] = mfma16(q0, kf[jf][0], s[jf]);
            #pragma unroll
            for (int jf = 0; jf < 4; ++jf) s[jf] = mfma16(q1, kf[jf][1], s[jf]);
            #pragma unroll
            for (int jf = 0; jf < 4; ++jf)
                csum[jf] += fast_exp2(s[jf][0]) + fast_exp2(s[jf][1])
                          + fast_exp2(s[jf][2]) + fast_exp2(s[jf][3]);
        }
    }
    #pragma unroll
    for (int jf = 0; jf < 4; ++jf) {
        csum[jf] += __shfl_xor(csum[jf], 16, 64);
        csum[jf] += __shfl_xor(csum[jf], 32, 64);
    }
    if (lane < 16)
        #pragma unroll
        for (int jf = 0; jf < 4; ++jf)
            part[((size_t)ic * BATCH * NH + bh) * NSRC + j0 + jf * 16 + lane] = csum[jf];
}

// ---------------- vscale2: fused csum-reduce + v/cs + 1/cs row + vsum ----------------
// grid (VROWS, 16): d<64: vT2=v/cs & vs=sum(v); d==64: vT2=1/cs
__global__ __launch_bounds__(256) void vscale2(const u16* __restrict__ vTh,
    const float* __restrict__ cs_part, float* __restrict__ vs, u16* __restrict__ vT2)
{
    int d = blockIdx.x;   // 0..64
    int bh = blockIdx.y;  // 0..15
    const int S = BATCH * NH * NSRC;
    const float* cp = cs_part + (size_t)bh * NSRC;
    u16* dst = vT2 + ((size_t)bh * VROWS + d) * NSRC;
    if (d == 64) {
        for (int j = threadIdx.x; j < NSRC; j += 256) {
            float cs = cp[j] + cp[j + S] + cp[j + 2 * S] + cp[j + 3 * S];
            dst[j] = f2bf(fast_rcp(cs));
        }
        return;
    }
    const u16* src = vTh + ((size_t)bh * HD + d) * NSRC;
    float acc = 0.f;
    for (int j = threadIdx.x; j < NSRC; j += 256) {
        float v = bf2f(src[j]);
        acc += v;
        float cs = cp[j] + cp[j + S] + cp[j + 2 * S] + cp[j + 3 * S];
        dst[j] = f2bf(v * fast_rcp(cs));
    }
    #pragma unroll
    for (int off = 32; off > 0; off >>= 1) acc += __shfl_down(acc, off, 64);
    __shared__ float r4[4];
    if ((threadIdx.x & 63) == 0) r4[threadIdx.x >> 6] = acc;
    __syncthreads();
    if (threadIdx.x == 0) vs[bh * HD + d] = r4[0] + r4[1] + r4[2] + r4[3];
}

// ---------------- pass B: dbuf; 2 i-frags/wave (K/V frag reuse); P=exp2(KQ^T) ----------------
// 1-D grid 512: id%8==bh%8; block covers 128 i (wave: 32), j-quarter loop
__global__ __launch_bounds__(256, 3) void pass_b(const u16* __restrict__ q,
    const u16* __restrict__ k, const u16* __restrict__ vT2,
    float* __restrict__ pv, float* __restrict__ rs)
{
    int id = blockIdx.x;
    int slot = id >> 3;              // 0..63
    int bh = (id & 7) + 8 * (slot >> 5);
    int rem = slot & 31;
    int split = rem >> 3;            // 0..3
    int i0 = (rem & 7) * 128;        // 0..896
    int t = threadIdx.x, wave = t >> 6, lane = t & 63;
    const u16* qb = q + (size_t)bh * NSINK * HD;
    const u16* kb = k + (size_t)bh * NSRC * HD;
    const u16* vb = vT2 + (size_t)bh * VROWS * NSRC;

    __shared__ u16 Ks[2][64 * 64];
    __shared__ u16 Vs[2][64 * 64];
    __shared__ alignas(16) u16 Rcs[2][64];
    __shared__ alignas(16) u16 pbuf[4][2][16 * 76];   // [wave][fi][i][j], stride 76

    short8 qf[2][2];   // [fi][kc]
    #pragma unroll
    for (int fi = 0; fi < 2; ++fi)
        #pragma unroll
        for (int kc = 0; kc < 2; ++kc)
            qf[fi][kc] = ldfrag(qb + (size_t)(i0 + wave * 32 + fi * 16) * HD + kc * 32, HD, lane);

    auto stage = [&](int buf, int jt) {
        int j0 = split * (NSRC / 4) + jt * 64;
        stage_tile<64>(Ks[buf], kb + (size_t)j0 * HD, HD, t);
        stage_tile<64>(Vs[buf], vb + j0, NSRC, t);
        if (t < 8) gld16(vb + (size_t)64 * NSRC + j0 + t * 8, Rcs[buf]);
    };

    f32x4 o[2][5] = {};
    stage(0, 0);
    __syncthreads();
    int cur = 0;
    for (int jt = 0; jt < 16; ++jt) {
        if (jt + 1 < 16) stage(cur ^ 1, jt + 1);   // prefetch overlaps compute
        // swapped QK^T: each K frag read once, feeds both i-frags
        f32x4 s[2][4] = {};
        #pragma unroll
        for (int kc = 0; kc < 2; ++kc)
            #pragma unroll
            for (int jf = 0; jf < 4; ++jf) {
                short8 kf = rdfrag(Ks[cur], jf * 16, kc * 4, lane);
                s[0][jf] = mfma16(kf, qf[0][kc], s[0][jf]);
                s[1][jf] = mfma16(kf, qf[1][kc], s[1][jf]);
            }
        // P̃ = exp2(S) -> bf16, one b64 write per (fi,jf)
        #pragma unroll
        for (int fi = 0; fi < 2; ++fi)
            #pragma unroll
            for (int jf = 0; jf < 4; ++jf) {
                uint2 w;
                w.x = pk_bf16(fast_exp2(s[fi][jf][0]), fast_exp2(s[fi][jf][1]));
                w.y = pk_bf16(fast_exp2(s[fi][jf][2]), fast_exp2(s[fi][jf][3]));
                *(uint2*)&pbuf[wave][fi][(size_t)(lane & 15) * 76 + jf * 16 + (lane >> 4) * 4] = w;
            }
        // PV: each V frag read once, feeds both i-frags; 5th frag = 1/cs (rowsum)
        short8 z = {};
        #pragma unroll
        for (int jc = 0; jc < 2; ++jc) {
            short8 pa0 = *(const short8*)&pbuf[wave][0][(size_t)(lane & 15) * 76 + jc * 32 + (lane >> 4) * 8];
            short8 pa1 = *(const short8*)&pbuf[wave][1][(size_t)(lane & 15) * 76 + jc * 32 + (lane >> 4) * 8];
            #pragma unroll
            for (int df = 0; df < 4; ++df) {
                short8 vf = rdfrag(Vs[cur], df * 16, jc * 4, lane);
                o[0][df] = mfma16(pa0, vf, o[0][df]);
                o[1][df] = mfma16(pa1, vf, o[1][df]);
            }
            short8 b5 = z;
            if ((lane & 15) == 0)
                b5 = *(const short8*)&Rcs[cur][jc * 32 + (lane >> 4) * 8];
            o[0][4] = mfma16(pa0, b5, o[0][4]);
            o[1][4] = mfma16(pa1, b5, o[1][4]);
        }
        __syncthreads();   // drains prefetch vmcnt; guards buffer reuse
        cur ^= 1;
    }
    // rowsum = o[fi][4] col 0 (lanes with lane&15==0)
    if ((lane & 15) == 0) {
        #pragma unroll
        for (int fi = 0; fi < 2; ++fi)
            #pragma unroll
            for (int r = 0; r < 4; ++r)
                rs[((size_t)split * (BATCH * NH) + bh) * NSINK + i0 + wave * 32 + fi * 16 + (lane >> 4) * 4 + r] = o[fi][4][r];
    }
    int b = bh >> 3, h = bh & 7;
    float* pvp = pv + (size_t)split * BATCH * NSINK * DIM;
    #pragma unroll
    for (int fi = 0; fi < 2; ++fi)
        #pragma unroll
        for (int df = 0; df < 4; ++df)
            #pragma unroll
            for (int r = 0; r < 4; ++r) {
                int row = i0 + wave * 32 + fi * 16 + (lane >> 4) * 4 + r;
                pvp[((size_t)(b * NSINK + row)) * DIM + h * HD + df * 16 + (lane & 15)] = o[fi][df][r];
            }
}

// ---------------- finalize: a = (sum pv + eps*vsum)/(sum rs + Neps) -> bf16 ----------------
__global__ __launch_bounds__(256) void finalize_pv(const float* __restrict__ pv,
    const float* __restrict__ rs, const float* __restrict__ vs,
    u16* __restrict__ ab)
{
    const int M = BATCH * NSINK * DIM;
    const int R = BATCH * NH * NSINK;
    int idx = blockIdx.x * 256 + threadIdx.x;
    int m = idx >> 9, n = idx & 511;
    int b = m >> 10, i = m & 1023, h = n >> 6, d = n & 63;
    int bh = b * NH + h;
    float val = pv[idx] + pv[idx + M] + pv[idx + 2 * M] + pv[idx + 3 * M]
              + EPS * vs[bh * HD + d];
    float rsv = rs[bh * NSINK + i] + rs[R + bh * NSINK + i]
              + rs[2 * R + bh * NSINK + i] + rs[3 * R + bh * NSINK + i]
              + (float)NSRC * EPS;
    ab[idx] = f2bf(val / rsv);
}

extern "C" void kernel_launch(void* const* d_in, const int* in_sizes, int n_in,
                              void* d_out, int out_size, void* d_ws, size_t ws_size,
                              hipStream_t stream) {
    (void)in_sizes; (void)n_in; (void)out_size;
    const float* sink    = (const float*)d_in[0];
    const float* source  = (const float*)d_in[1];
    const float* gamma_s = (const float*)d_in[2];
    const float* beta_s  = (const float*)d_in[3];
    const float* gamma_c = (const float*)d_in[4];
    const float* beta_c  = (const float*)d_in[5];
    const float* Wq      = (const float*)d_in[6];
    const float* bq      = (const float*)d_in[7];
    const float* Wkv     = (const float*)d_in[8];
    const float* bkv     = (const float*)d_in[9];
    const float* Wo      = (const float*)d_in[10];
    const float* bo      = (const float*)d_in[11];
    float* out = (float*)d_out;

    char* p = (char*)d_ws;
    auto carve = [&](size_t bytes) { char* r = p; p += (bytes + 255) & ~(size_t)255; return r; };
    u16* sh    = (u16*)carve(2048ull * 512 * 2);       // LN'd sink
    u16* ch    = (u16*)carve(8192ull * 512 * 2);       // LN'd source
    u16* wqT   = (u16*)carve(512ull * 512 * 2);
    u16* wkvT  = (u16*)carve(1024ull * 512 * 2);
    u16* woT   = (u16*)carve(512ull * 512 * 2);
    u16* qb    = (u16*)carve(16ull * 1024 * 64 * 2);
    u16* kb    = (u16*)carve(16ull * 4096 * 64 * 2);
    u16* vTh   = (u16*)carve(16ull * 64 * 4096 * 2);
    u16* vT2   = (u16*)carve(16ull * VROWS * 4096 * 2);
    float* cs_part = (float*)carve(4ull * 16 * 4096 * 4);
    float* vs      = (float*)carve(1024ull * 4);
    float* rs      = (float*)carve(4ull * 16 * 1024 * 4);
    float* pv      = (float*)carve(4ull * 2048 * 512 * 4);
    u16*   ab      = (u16*)carve(2048ull * 512 * 2);
    if ((size_t)(p - (char*)d_ws) > ws_size) return;

    ln_all<<<BATCH * (NSINK + NSRC), 256, 0, stream>>>(
        sink, source, gamma_s, beta_s, gamma_c, beta_c, sh, ch);
    wt_all<<<2048, 256, 0, stream>>>(Wq, Wkv, Wo, wqT, wkvT, woT);

    gemm1<1, 64, 64><<<dim3(DIM / 64, BATCH * NSINK / 64), 256, 0, stream>>>(
        sh, wqT, bq, 512, nullptr, qb, nullptr);
    gemm1<2, 128, 128><<<dim3(2 * DIM / 128, BATCH * NSRC / 128), 256, 0, stream>>>(
        ch, wkvT, bkv, 512, nullptr, kb, vTh);

    pass_a<<<1024, 256, 0, stream>>>(qb, kb, cs_part);
    vscale2<<<dim3(VROWS, BATCH * NH), 256, 0, stream>>>(vTh, cs_part, vs, vT2);
    pass_b<<<512, 256, 0, stream>>>(qb, kb, vT2, pv, rs);
    finalize_pv<<<4096, 256, 0, stream>>>(pv, rs, vs, ab);

    gemm1<0, 64, 64><<<dim3(DIM / 64, BATCH * NSINK / 64), 256, 0, stream>>>(
        ab, woT, bo, 512, out, nullptr, nullptr);
}

// Round 11
// 111.571 us; speedup vs baseline: 2.4009x; 1.1397x over previous
//
#include <hip/hip_runtime.h>
#include <hip/hip_bf16.h>
#include <math.h>

#define EPS 1e-6f
#define NSINK 1024
#define NSRC 4096
#define DIM 512
#define NH 8
#define HD 64
#define BATCH 2
#define VROWS 65   // extended V: 0..63 = v/cs, 64 = 1/cs
// fold (d^-0.5 = 1/8) * log2(e) into q so sim exp is a single exp2
#define QSCALE 0.18033688011112042f

typedef unsigned short u16;
typedef __attribute__((ext_vector_type(8))) short short8;
typedef __attribute__((ext_vector_type(4))) float f32x4;

__device__ inline float fast_exp2(float x) {
#if __has_builtin(__builtin_amdgcn_exp2f)
    return __builtin_amdgcn_exp2f(x);
#else
    return exp2f(x);
#endif
}
__device__ inline float fast_rcp(float x) {
#if __has_builtin(__builtin_amdgcn_rcpf)
    return __builtin_amdgcn_rcpf(x);
#else
    return 1.0f / x;
#endif
}
__device__ inline u16 f2bf(float x) {
    union { float f; unsigned u; } v; v.f = x;
    unsigned r = v.u + 0x7fffu + ((v.u >> 16) & 1u);
    return (u16)(r >> 16);
}
__device__ inline float bf2f(u16 h) {
    union { unsigned u; float f; } v; v.u = ((unsigned)h) << 16;
    return v.f;
}
// pack 2 f32 -> 2 bf16 (RTNE) in one u32; lowers to v_cvt_pk_bf16_f32
__device__ inline unsigned pk_bf16(float a, float b) {
    union { __hip_bfloat162 h; unsigned u; } v;
    v.h = __float22bfloat162_rn(make_float2(a, b));
    return v.u;
}
__device__ inline f32x4 mfma16(short8 a, short8 b, f32x4 c) {
    return __builtin_amdgcn_mfma_f32_16x16x32_bf16(a, b, c, 0, 0, 0);
}
// direct-from-global fragment loader
__device__ inline short8 ldfrag(const u16* base, int stride, int lane) {
    return *(const short8*)(base + (size_t)(lane & 15) * stride + ((lane >> 4) << 3));
}

// async global->LDS, 16B per lane
__device__ inline void gld16(const u16* g, u16* l) {
    __builtin_amdgcn_global_load_lds(
        (const __attribute__((address_space(1))) unsigned*)g,
        (__attribute__((address_space(3))) unsigned*)l, 16, 0, 0);
}

// stage a [TM][64] bf16 tile from gsrc (row-major, stride K);
// LDS linear dest; global source inverse-swizzled (c ^= m&7).
template<int TM>
__device__ inline void stage_tile(u16* lds, const u16* gsrc, int K, int t) {
    #pragma unroll
    for (int it = 0; it < TM / 32; ++it) {
        int m = it * 32 + (t >> 3);
        int c = (t & 7) ^ (m & 7);
        gld16(gsrc + (size_t)m * K + c * 8,
              lds + it * 2048 + (t >> 6) * 512);
    }
}
// swizzled fragment read
__device__ inline short8 rdfrag(const u16* tile, int fbase, int cbase, int lane) {
    int m = fbase + (lane & 15);
    int c = (cbase + (lane >> 4)) ^ (m & 7);
    return *(const short8*)(tile + (size_t)m * 64 + c * 8);
}

// ---------------- fused LayerNorm (both inputs) -> bf16 ----------------
__global__ __launch_bounds__(256) void ln_all(
    const float* __restrict__ sink, const float* __restrict__ source,
    const float* __restrict__ gs, const float* __restrict__ bs,
    const float* __restrict__ gc, const float* __restrict__ bc,
    u16* __restrict__ sh, u16* __restrict__ ch)
{
    int row = blockIdx.x;
    const float* xr; const float* g; const float* be; u16* y;
    if (row < BATCH * NSINK) {
        xr = sink + (size_t)row * DIM; g = gs; be = bs; y = sh + (size_t)row * DIM;
    } else {
        int rr = row - BATCH * NSINK;
        xr = source + (size_t)rr * DIM; g = gc; be = bc; y = ch + (size_t)rr * DIM;
    }
    int t = threadIdx.x;
    float v0 = xr[t], v1 = xr[t + 256];
    float s = v0 + v1, sq = v0 * v0 + v1 * v1;
    #pragma unroll
    for (int off = 32; off > 0; off >>= 1) {
        s  += __shfl_down(s, off, 64);
        sq += __shfl_down(sq, off, 64);
    }
    __shared__ float rsm[4], rq[4];
    int wave = t >> 6;
    if ((t & 63) == 0) { rsm[wave] = s; rq[wave] = sq; }
    __syncthreads();
    s  = rsm[0] + rsm[1] + rsm[2] + rsm[3];
    sq = rq[0] + rq[1] + rq[2] + rq[3];
    float mu = s * (1.0f / DIM);
    float var = sq * (1.0f / DIM) - mu * mu;
    float a = var + EPS;
    float r = rsqrtf(a);
    r = r * (1.5f - 0.5f * a * r * r);
    y[t]       = f2bf((v0 - mu) * r * g[t] + be[t]);
    y[t + 256] = f2bf((v1 - mu) * r * g[t + 256] + be[t + 256]);
}

// ---------------- fused weight transpose: all three W[K][N] -> T[N][K] bf16 ----------------
__global__ __launch_bounds__(256) void wt_all(
    const float* __restrict__ Wq, const float* __restrict__ Wkv, const float* __restrict__ Wo,
    u16* __restrict__ wqT, u16* __restrict__ wkvT, u16* __restrict__ woT)
{
    int n = blockIdx.x;   // 0..2047
    const float* W; u16* T; int N; int nn;
    if (n < 512)       { W = Wq;  T = wqT;  N = 512;  nn = n; }
    else if (n < 1536) { W = Wkv; T = wkvT; N = 1024; nn = n - 512; }
    else               { W = Wo;  T = woT;  N = 512;  nn = n - 1536; }
    for (int k = threadIdx.x; k < 512; k += 256)
        T[(size_t)nn * 512 + k] = f2bf(W[(size_t)k * N + nn]);
}

// ---------------- 1-term 2-phase LDS-dbuf MFMA GEMM: C = A @ BT^T + bias ----------------
// MODE 0: C fp32 row-major. MODE 1: q bf16 [bh][i][d] * QSCALE.
// MODE 2: n<512 -> k bf16 [bh][j][d]; n>=512 -> vT bf16 [bh*64+d][j].
// SWZ: 1-D grid, XCD-affine decode (id&7 = XCD, each XCD owns an 8-m-tile slab x all n)
template<int MODE, int TM, int TN, int SWZ>
__global__ __launch_bounds__(256) void gemm1(
    const u16* __restrict__ A, const u16* __restrict__ BT,
    const float* __restrict__ bias, int K,
    float* __restrict__ cf, u16* __restrict__ o1, u16* __restrict__ o2)
{
    constexpr int FM = TM / 32, FN = TN / 32;
    __shared__ u16 As[2][TM * 64];
    __shared__ u16 Bs[2][TN * 64];
    int t = threadIdx.x;
    int wave = t >> 6, lane = t & 63;
    int wr = wave >> 1, wc = wave & 1;
    int m0, n0;
    if constexpr (SWZ) {
        int id = blockIdx.x;            // 512 blocks: 64 m-tiles x 8 n-tiles
        int slot = id >> 3;             // 0..63
        m0 = ((id & 7) * 8 + (slot & 7)) * TM;
        n0 = (slot >> 3) * TN;
    } else {
        m0 = blockIdx.y * TM;
        n0 = blockIdx.x * TN;
    }

    f32x4 acc[FM][FN] = {};
    stage_tile<TM>(As[0], A + (size_t)m0 * K, K, t);
    stage_tile<TN>(Bs[0], BT + (size_t)n0 * K, K, t);
    __syncthreads();
    int nt = K >> 6;
    int cur = 0;
    for (int kt = 0; kt < nt; ++kt) {
        if (kt + 1 < nt) {
            stage_tile<TM>(As[cur ^ 1], A + (size_t)m0 * K + (kt + 1) * 64, K, t);
            stage_tile<TN>(Bs[cur ^ 1], BT + (size_t)n0 * K + (kt + 1) * 64, K, t);
        }
        #pragma unroll
        for (int kk = 0; kk < 2; ++kk) {
            short8 af[FM], bf[FN];
            #pragma unroll
            for (int f = 0; f < FM; ++f)
                af[f] = rdfrag(As[cur], wr * (TM / 2) + f * 16, kk * 4, lane);
            #pragma unroll
            for (int f = 0; f < FN; ++f)
                bf[f] = rdfrag(Bs[cur], wc * (TN / 2) + f * 16, kk * 4, lane);
            #pragma unroll
            for (int i = 0; i < FM; ++i)
                #pragma unroll
                for (int j = 0; j < FN; ++j)
                    acc[i][j] = mfma16(af[i], bf[j], acc[i][j]);
        }
        __syncthreads();
        cur ^= 1;
    }

    #pragma unroll
    for (int i = 0; i < FM; ++i)
        #pragma unroll
        for (int j = 0; j < FN; ++j)
            #pragma unroll
            for (int r = 0; r < 4; ++r) {
                int m = m0 + wr * (TM / 2) + i * 16 + (lane >> 4) * 4 + r;
                int n = n0 + wc * (TN / 2) + j * 16 + (lane & 15);
                float v = acc[i][j][r] + bias[n];
                if (MODE == 0) {
                    cf[(size_t)m * DIM + n] = v;
                } else if (MODE == 1) {
                    int b = m >> 10, ii = m & 1023;
                    int h = n >> 6, d = n & 63;
                    o1[((size_t)(b * NH + h) * NSINK + ii) * HD + d] = f2bf(v * QSCALE);
                } else {
                    int b = m >> 12, jj = m & 4095;
                    if (n < DIM) {
                        int h = n >> 6, d = n & 63;
                        o1[((size_t)(b * NH + h) * NSRC + jj) * HD + d] = f2bf(v);
                    } else {
                        int nn = n - DIM;
                        int h = nn >> 6, d = nn & 63;
                        o2[((size_t)(b * NH + h) * HD + d) * NSRC + jj] = f2bf(v);
                    }
                }
            }
}

// ---------------- pass A: colsum_part[ic][bh][j] = sum_{i chunk} exp2(q.k) ----------------
// q staged in LDS (shared by 4 waves, dbuf); k frags in regs (loaded once)
__global__ __launch_bounds__(256, 4) void pass_a(const u16* __restrict__ q,
    const u16* __restrict__ k, float* __restrict__ part)
{
    int id = blockIdx.x;
    int slot = id >> 3;
    int bh = (id & 7) + 8 * (slot >> 6);
    int rem = slot & 63;
    int ic = rem >> 4;
    int t = threadIdx.x, wave = t >> 6, lane = t & 63;
    int j0 = (rem & 15) * 256 + wave * 64;
    const u16* qb = q + (size_t)bh * NSINK * HD;
    const u16* kb = k + (size_t)bh * NSRC * HD;

    __shared__ u16 Qs[2][64 * 64];

    short8 kf[4][2];
    #pragma unroll
    for (int jf = 0; jf < 4; ++jf)
        #pragma unroll
        for (int kc = 0; kc < 2; ++kc)
            kf[jf][kc] = ldfrag(kb + (size_t)(j0 + jf * 16) * HD + kc * 32, HD, lane);

    float csum[4] = {};
    stage_tile<64>(Qs[0], qb + (size_t)(ic * 256) * HD, HD, t);
    __syncthreads();
    int cur = 0;
    for (int ii = 0; ii < 4; ++ii) {
        if (ii + 1 < 4)
            stage_tile<64>(Qs[cur ^ 1], qb + (size_t)(ic * 256 + (ii + 1) * 64) * HD, HD, t);
        #pragma unroll
        for (int f = 0; f < 4; ++f) {
            short8 q0 = rdfrag(Qs[cur], f * 16, 0, lane);
            short8 q1 = rdfrag(Qs[cur], f * 16, 4, lane);
            f32x4 s[4] = {};
            #pragma unroll
            for (int jf = 0; jf < 4; ++jf) s[jf] = mfma16(q0, kf[jf][0], s[jf]);
            #pragma unroll
            for (int jf = 0; jf < 4; ++jf) s[jf] = mfma16(q1, kf[jf][1], s[jf]);
            #pragma unroll
            for (int jf = 0; jf < 4; ++jf)
                csum[jf] += fast_exp2(s[jf][0]) + fast_exp2(s[jf][1])
                          + fast_exp2(s[jf][2]) + fast_exp2(s[jf][3]);
        }
        __syncthreads();   // drains prefetch vmcnt; guards buffer reuse
        cur ^= 1;
    }
    #pragma unroll
    for (int jf = 0; jf < 4; ++jf) {
        csum[jf] += __shfl_xor(csum[jf], 16, 64);
        csum[jf] += __shfl_xor(csum[jf], 32, 64);
    }
    if (lane < 16)
        #pragma unroll
        for (int jf = 0; jf < 4; ++jf)
            part[((size_t)ic * BATCH * NH + bh) * NSRC + j0 + jf * 16 + lane] = csum[jf];
}

// ---------------- vscale2: fused csum-reduce + v/cs + 1/cs row + vsum ----------------
// grid (VROWS, 16): d<64: vT2=v/cs & vs=sum(v); d==64: vT2=1/cs
__global__ __launch_bounds__(256) void vscale2(const u16* __restrict__ vTh,
    const float* __restrict__ cs_part, float* __restrict__ vs, u16* __restrict__ vT2)
{
    int d = blockIdx.x;   // 0..64
    int bh = blockIdx.y;  // 0..15
    const int S = BATCH * NH * NSRC;
    const float* cp = cs_part + (size_t)bh * NSRC;
    u16* dst = vT2 + ((size_t)bh * VROWS + d) * NSRC;
    if (d == 64) {
        for (int j = threadIdx.x; j < NSRC; j += 256) {
            float cs = cp[j] + cp[j + S] + cp[j + 2 * S] + cp[j + 3 * S];
            dst[j] = f2bf(fast_rcp(cs));
        }
        return;
    }
    const u16* src = vTh + ((size_t)bh * HD + d) * NSRC;
    float acc = 0.f;
    for (int j = threadIdx.x; j < NSRC; j += 256) {
        float v = bf2f(src[j]);
        acc += v;
        float cs = cp[j] + cp[j + S] + cp[j + 2 * S] + cp[j + 3 * S];
        dst[j] = f2bf(v * fast_rcp(cs));
    }
    #pragma unroll
    for (int off = 32; off > 0; off >>= 1) acc += __shfl_down(acc, off, 64);
    __shared__ float r4[4];
    if ((threadIdx.x & 63) == 0) r4[threadIdx.x >> 6] = acc;
    __syncthreads();
    if (threadIdx.x == 0) vs[bh * HD + d] = r4[0] + r4[1] + r4[2] + r4[3];
}

// ---------------- pass B: dbuf; 2 i-frags/wave (K/V frag reuse); P=exp2(KQ^T) ----------------
// 1-D grid 512: id%8==bh%8; block covers 128 i (wave: 32), j-quarter loop
__global__ __launch_bounds__(256, 3) void pass_b(const u16* __restrict__ q,
    const u16* __restrict__ k, const u16* __restrict__ vT2,
    float* __restrict__ pv, float* __restrict__ rs)
{
    int id = blockIdx.x;
    int slot = id >> 3;              // 0..63
    int bh = (id & 7) + 8 * (slot >> 5);
    int rem = slot & 31;
    int split = rem >> 3;            // 0..3
    int i0 = (rem & 7) * 128;        // 0..896
    int t = threadIdx.x, wave = t >> 6, lane = t & 63;
    const u16* qb = q + (size_t)bh * NSINK * HD;
    const u16* kb = k + (size_t)bh * NSRC * HD;
    const u16* vb = vT2 + (size_t)bh * VROWS * NSRC;

    __shared__ u16 Ks[2][64 * 64];
    __shared__ u16 Vs[2][64 * 64];
    __shared__ alignas(16) u16 Rcs[2][64];
    __shared__ alignas(16) u16 pbuf[4][2][16 * 76];   // [wave][fi][i][j], stride 76

    short8 qf[2][2];   // [fi][kc]
    #pragma unroll
    for (int fi = 0; fi < 2; ++fi)
        #pragma unroll
        for (int kc = 0; kc < 2; ++kc)
            qf[fi][kc] = ldfrag(qb + (size_t)(i0 + wave * 32 + fi * 16) * HD + kc * 32, HD, lane);

    auto stage = [&](int buf, int jt) {
        int j0 = split * (NSRC / 4) + jt * 64;
        stage_tile<64>(Ks[buf], kb + (size_t)j0 * HD, HD, t);
        stage_tile<64>(Vs[buf], vb + j0, NSRC, t);
        if (t < 8) gld16(vb + (size_t)64 * NSRC + j0 + t * 8, Rcs[buf]);
    };

    f32x4 o[2][5] = {};
    stage(0, 0);
    __syncthreads();
    int cur = 0;
    for (int jt = 0; jt < 16; ++jt) {
        if (jt + 1 < 16) stage(cur ^ 1, jt + 1);   // prefetch overlaps compute
        // swapped QK^T: each K frag read once, feeds both i-frags
        f32x4 s[2][4] = {};
        #pragma unroll
        for (int kc = 0; kc < 2; ++kc)
            #pragma unroll
            for (int jf = 0; jf < 4; ++jf) {
                short8 kf = rdfrag(Ks[cur], jf * 16, kc * 4, lane);
                s[0][jf] = mfma16(kf, qf[0][kc], s[0][jf]);
                s[1][jf] = mfma16(kf, qf[1][kc], s[1][jf]);
            }
        // P̃ = exp2(S) -> bf16, one b64 write per (fi,jf)
        #pragma unroll
        for (int fi = 0; fi < 2; ++fi)
            #pragma unroll
            for (int jf = 0; jf < 4; ++jf) {
                uint2 w;
                w.x = pk_bf16(fast_exp2(s[fi][jf][0]), fast_exp2(s[fi][jf][1]));
                w.y = pk_bf16(fast_exp2(s[fi][jf][2]), fast_exp2(s[fi][jf][3]));
                *(uint2*)&pbuf[wave][fi][(size_t)(lane & 15) * 76 + jf * 16 + (lane >> 4) * 4] = w;
            }
        // PV: each V frag read once, feeds both i-frags; 5th frag = 1/cs (rowsum)
        short8 z = {};
        #pragma unroll
        for (int jc = 0; jc < 2; ++jc) {
            short8 pa0 = *(const short8*)&pbuf[wave][0][(size_t)(lane & 15) * 76 + jc * 32 + (lane >> 4) * 8];
            short8 pa1 = *(const short8*)&pbuf[wave][1][(size_t)(lane & 15) * 76 + jc * 32 + (lane >> 4) * 8];
            #pragma unroll
            for (int df = 0; df < 4; ++df) {
                short8 vf = rdfrag(Vs[cur], df * 16, jc * 4, lane);
                o[0][df] = mfma16(pa0, vf, o[0][df]);
                o[1][df] = mfma16(pa1, vf, o[1][df]);
            }
            short8 b5 = z;
            if ((lane & 15) == 0)
                b5 = *(const short8*)&Rcs[cur][jc * 32 + (lane >> 4) * 8];
            o[0][4] = mfma16(pa0, b5, o[0][4]);
            o[1][4] = mfma16(pa1, b5, o[1][4]);
        }
        __syncthreads();   // drains prefetch vmcnt; guards buffer reuse
        cur ^= 1;
    }
    // rowsum = o[fi][4] col 0 (lanes with lane&15==0)
    if ((lane & 15) == 0) {
        #pragma unroll
        for (int fi = 0; fi < 2; ++fi)
            #pragma unroll
            for (int r = 0; r < 4; ++r)
                rs[((size_t)split * (BATCH * NH) + bh) * NSINK + i0 + wave * 32 + fi * 16 + (lane >> 4) * 4 + r] = o[fi][4][r];
    }
    int b = bh >> 3, h = bh & 7;
    float* pvp = pv + (size_t)split * BATCH * NSINK * DIM;
    #pragma unroll
    for (int fi = 0; fi < 2; ++fi)
        #pragma unroll
        for (int df = 0; df < 4; ++df)
            #pragma unroll
            for (int r = 0; r < 4; ++r) {
                int row = i0 + wave * 32 + fi * 16 + (lane >> 4) * 4 + r;
                pvp[((size_t)(b * NSINK + row)) * DIM + h * HD + df * 16 + (lane & 15)] = o[fi][df][r];
            }
}

// ---------------- finalize: a = (sum pv + eps*vsum)/(sum rs + Neps) -> bf16 ----------------
__global__ __launch_bounds__(256) void finalize_pv(const float* __restrict__ pv,
    const float* __restrict__ rs, const float* __restrict__ vs,
    u16* __restrict__ ab)
{
    const int M = BATCH * NSINK * DIM;
    const int R = BATCH * NH * NSINK;
    int idx = blockIdx.x * 256 + threadIdx.x;
    int m = idx >> 9, n = idx & 511;
    int b = m >> 10, i = m & 1023, h = n >> 6, d = n & 63;
    int bh = b * NH + h;
    float val = pv[idx] + pv[idx + M] + pv[idx + 2 * M] + pv[idx + 3 * M]
              + EPS * vs[bh * HD + d];
    float rsv = rs[bh * NSINK + i] + rs[R + bh * NSINK + i]
              + rs[2 * R + bh * NSINK + i] + rs[3 * R + bh * NSINK + i]
              + (float)NSRC * EPS;
    ab[idx] = f2bf(val / rsv);
}

extern "C" void kernel_launch(void* const* d_in, const int* in_sizes, int n_in,
                              void* d_out, int out_size, void* d_ws, size_t ws_size,
                              hipStream_t stream) {
    (void)in_sizes; (void)n_in; (void)out_size;
    const float* sink    = (const float*)d_in[0];
    const float* source  = (const float*)d_in[1];
    const float* gamma_s = (const float*)d_in[2];
    const float* beta_s  = (const float*)d_in[3];
    const float* gamma_c = (const float*)d_in[4];
    const float* beta_c  = (const float*)d_in[5];
    const float* Wq      = (const float*)d_in[6];
    const float* bq      = (const float*)d_in[7];
    const float* Wkv     = (const float*)d_in[8];
    const float* bkv     = (const float*)d_in[9];
    const float* Wo      = (const float*)d_in[10];
    const float* bo      = (const float*)d_in[11];
    float* out = (float*)d_out;

    char* p = (char*)d_ws;
    auto carve = [&](size_t bytes) { char* r = p; p += (bytes + 255) & ~(size_t)255; return r; };
    u16* sh    = (u16*)carve(2048ull * 512 * 2);       // LN'd sink
    u16* ch    = (u16*)carve(8192ull * 512 * 2);       // LN'd source
    u16* wqT   = (u16*)carve(512ull * 512 * 2);
    u16* wkvT  = (u16*)carve(1024ull * 512 * 2);
    u16* woT   = (u16*)carve(512ull * 512 * 2);
    u16* qb    = (u16*)carve(16ull * 1024 * 64 * 2);
    u16* kb    = (u16*)carve(16ull * 4096 * 64 * 2);
    u16* vTh   = (u16*)carve(16ull * 64 * 4096 * 2);
    u16* vT2   = (u16*)carve(16ull * VROWS * 4096 * 2);
    float* cs_part = (float*)carve(4ull * 16 * 4096 * 4);
    float* vs      = (float*)carve(1024ull * 4);
    float* rs      = (float*)carve(4ull * 16 * 1024 * 4);
    float* pv      = (float*)carve(4ull * 2048 * 512 * 4);
    u16*   ab      = (u16*)carve(2048ull * 512 * 2);
    if ((size_t)(p - (char*)d_ws) > ws_size) return;

    ln_all<<<BATCH * (NSINK + NSRC), 256, 0, stream>>>(
        sink, source, gamma_s, beta_s, gamma_c, beta_c, sh, ch);
    wt_all<<<2048, 256, 0, stream>>>(Wq, Wkv, Wo, wqT, wkvT, woT);

    gemm1<1, 64, 64, 0><<<dim3(DIM / 64, BATCH * NSINK / 64), 256, 0, stream>>>(
        sh, wqT, bq, 512, nullptr, qb, nullptr);
    // KV: XCD-affine 1-D grid (64 m-tiles x 8 n-tiles)
    gemm1<2, 128, 128, 1><<<512, 256, 0, stream>>>(
        ch, wkvT, bkv, 512, nullptr, kb, vTh);

    pass_a<<<1024, 256, 0, stream>>>(qb, kb, cs_part);
    vscale2<<<dim3(VROWS, BATCH * NH), 256, 0, stream>>>(vTh, cs_part, vs, vT2);
    pass_b<<<512, 256, 0, stream>>>(qb, kb, vT2, pv, rs);
    finalize_pv<<<4096, 256, 0, stream>>>(pv, rs, vs, ab);

    gemm1<0, 64, 64, 0><<<dim3(DIM / 64, BATCH * NSINK / 64), 256, 0, stream>>>(
        ab, woT, bo, 512, out, nullptr, nullptr);
}

// Round 12
// 106.376 us; speedup vs baseline: 2.5181x; 1.0488x over previous
//
#include <hip/hip_runtime.h>
#include <hip/hip_bf16.h>
#include <math.h>

#define EPS 1e-6f
#define NSINK 1024
#define NSRC 4096
#define DIM 512
#define NH 8
#define HD 64
#define BATCH 2
#define VROWS 65   // extended V: 0..63 = v/cs, 64 = 1/cs
// fold (d^-0.5 = 1/8) * log2(e) into q so sim exp is a single exp2
#define QSCALE 0.18033688011112042f

#if __has_builtin(__builtin_amdgcn_permlane32_swap) && __has_builtin(__builtin_amdgcn_permlane16_swap)
#define HAVE_PERMLANE 1
#else
#define HAVE_PERMLANE 0
#endif

typedef unsigned short u16;
typedef __attribute__((ext_vector_type(8))) short short8;
typedef __attribute__((ext_vector_type(4))) float f32x4;

__device__ inline float fast_exp2(float x) {
#if __has_builtin(__builtin_amdgcn_exp2f)
    return __builtin_amdgcn_exp2f(x);
#else
    return exp2f(x);
#endif
}
__device__ inline float fast_rcp(float x) {
#if __has_builtin(__builtin_amdgcn_rcpf)
    return __builtin_amdgcn_rcpf(x);
#else
    return 1.0f / x;
#endif
}
__device__ inline u16 f2bf(float x) {
    union { float f; unsigned u; } v; v.f = x;
    unsigned r = v.u + 0x7fffu + ((v.u >> 16) & 1u);
    return (u16)(r >> 16);
}
__device__ inline float bf2f(u16 h) {
    union { unsigned u; float f; } v; v.u = ((unsigned)h) << 16;
    return v.f;
}
// pack 2 f32 -> 2 bf16 (RTNE) in one u32; lowers to v_cvt_pk_bf16_f32
__device__ inline unsigned pk_bf16(float a, float b) {
    union { __hip_bfloat162 h; unsigned u; } v;
    v.h = __float22bfloat162_rn(make_float2(a, b));
    return v.u;
}
__device__ inline f32x4 mfma16(short8 a, short8 b, f32x4 c) {
    return __builtin_amdgcn_mfma_f32_16x16x32_bf16(a, b, c, 0, 0, 0);
}
// direct-from-global fragment loader
__device__ inline short8 ldfrag(const u16* base, int stride, int lane) {
    return *(const short8*)(base + (size_t)(lane & 15) * stride + ((lane >> 4) << 3));
}

// async global->LDS, 16B per lane
__device__ inline void gld16(const u16* g, u16* l) {
    __builtin_amdgcn_global_load_lds(
        (const __attribute__((address_space(1))) unsigned*)g,
        (__attribute__((address_space(3))) unsigned*)l, 16, 0, 0);
}

// stage a [TM][64] bf16 tile from gsrc (row-major, stride K);
// LDS linear dest; global source inverse-swizzled (c ^= m&7).
template<int TM>
__device__ inline void stage_tile(u16* lds, const u16* gsrc, int K, int t) {
    #pragma unroll
    for (int it = 0; it < TM / 32; ++it) {
        int m = it * 32 + (t >> 3);
        int c = (t & 7) ^ (m & 7);
        gld16(gsrc + (size_t)m * K + c * 8,
              lds + it * 2048 + (t >> 6) * 512);
    }
}
// swizzled fragment read
__device__ inline short8 rdfrag(const u16* tile, int fbase, int cbase, int lane) {
    int m = fbase + (lane & 15);
    int c = (cbase + (lane >> 4)) ^ (m & 7);
    return *(const short8*)(tile + (size_t)m * 64 + c * 8);
}

#if HAVE_PERMLANE
// Build the PV A-fragment in-register from swapped-QK scores.
// Input: sA = s[2jc] (j 16-block 0), sB = s[2jc+1] (j 16-block 1); lane group
// g=(l>>4) holds j=4g..4g+3 of each block at fixed i=l&15.
// Output: lane l holds P[i=l&15][j = jc*32 + g*8 .. +8] as 8 bf16.
__device__ inline short8 pa_frag(const f32x4 sA, const f32x4 sB) {
    unsigned A0 = pk_bf16(sA[0], sA[1]);
    unsigned A1 = pk_bf16(sA[2], sA[3]);
    unsigned B0 = pk_bf16(sB[0], sB[1]);
    unsigned B1 = pk_bf16(sB[2], sB[3]);
    auto c0 = __builtin_amdgcn_permlane32_swap(A0, B0, false, false);
    auto c1 = __builtin_amdgcn_permlane32_swap(A1, B1, false, false);
    auto d0 = __builtin_amdgcn_permlane16_swap(c0[0], c0[1], false, false);
    auto d1 = __builtin_amdgcn_permlane16_swap(c1[0], c1[1], false, false);
    union { unsigned u[4]; short8 s8; } r;
    r.u[0] = d0[0]; r.u[1] = d1[0]; r.u[2] = d0[1]; r.u[3] = d1[1];
    return r.s8;
}
#endif

// ---------------- prep: fused LayerNorm (both inputs) + weight transposes ----------------
__global__ __launch_bounds__(256) void prep(
    const float* __restrict__ sink, const float* __restrict__ source,
    const float* __restrict__ gs, const float* __restrict__ bs,
    const float* __restrict__ gc, const float* __restrict__ bc,
    const float* __restrict__ Wq, const float* __restrict__ Wkv,
    const float* __restrict__ Wo,
    u16* __restrict__ sh, u16* __restrict__ ch,
    u16* __restrict__ wqT, u16* __restrict__ wkvT, u16* __restrict__ woT)
{
    int row = blockIdx.x;
    int t = threadIdx.x;
    if (row >= BATCH * (NSINK + NSRC)) {   // weight transpose blocks
        int n = row - BATCH * (NSINK + NSRC);
        const float* W; u16* T; int N; int nn;
        if (n < 512)       { W = Wq;  T = wqT;  N = 512;  nn = n; }
        else if (n < 1536) { W = Wkv; T = wkvT; N = 1024; nn = n - 512; }
        else               { W = Wo;  T = woT;  N = 512;  nn = n - 1536; }
        for (int k = t; k < 512; k += 256)
            T[(size_t)nn * 512 + k] = f2bf(W[(size_t)k * N + nn]);
        return;
    }
    const float* xr; const float* g; const float* be; u16* y;
    if (row < BATCH * NSINK) {
        xr = sink + (size_t)row * DIM; g = gs; be = bs; y = sh + (size_t)row * DIM;
    } else {
        int rr = row - BATCH * NSINK;
        xr = source + (size_t)rr * DIM; g = gc; be = bc; y = ch + (size_t)rr * DIM;
    }
    float v0 = xr[t], v1 = xr[t + 256];
    float s = v0 + v1, sq = v0 * v0 + v1 * v1;
    #pragma unroll
    for (int off = 32; off > 0; off >>= 1) {
        s  += __shfl_down(s, off, 64);
        sq += __shfl_down(sq, off, 64);
    }
    __shared__ float rsm[4], rq[4];
    int wave = t >> 6;
    if ((t & 63) == 0) { rsm[wave] = s; rq[wave] = sq; }
    __syncthreads();
    s  = rsm[0] + rsm[1] + rsm[2] + rsm[3];
    sq = rq[0] + rq[1] + rq[2] + rq[3];
    float mu = s * (1.0f / DIM);
    float var = sq * (1.0f / DIM) - mu * mu;
    float a = var + EPS;
    float r = rsqrtf(a);
    r = r * (1.5f - 0.5f * a * r * r);
    y[t]       = f2bf((v0 - mu) * r * g[t] + be[t]);
    y[t + 256] = f2bf((v1 - mu) * r * g[t + 256] + be[t + 256]);
}

// ---------------- 1-term 2-phase LDS-dbuf MFMA GEMM: C = A @ BT^T + bias ----------------
// MODE 0: C fp32 row-major. MODE 1: q bf16 [bh][i][d] * QSCALE.
// MODE 2: n<512 -> k bf16 [bh][j][d]; n>=512 -> vT bf16 [bh*64+d][j].
// SWZ: 1-D grid, XCD-affine decode (id&7 = XCD, each XCD owns an 8-m-tile slab x all n)
template<int MODE, int TM, int TN, int SWZ>
__global__ __launch_bounds__(256) void gemm1(
    const u16* __restrict__ A, const u16* __restrict__ BT,
    const float* __restrict__ bias, int K,
    float* __restrict__ cf, u16* __restrict__ o1, u16* __restrict__ o2)
{
    constexpr int FM = TM / 32, FN = TN / 32;
    __shared__ u16 As[2][TM * 64];
    __shared__ u16 Bs[2][TN * 64];
    int t = threadIdx.x;
    int wave = t >> 6, lane = t & 63;
    int wr = wave >> 1, wc = wave & 1;
    int m0, n0;
    if constexpr (SWZ) {
        int id = blockIdx.x;            // 512 blocks: 64 m-tiles x 8 n-tiles
        int slot = id >> 3;             // 0..63
        m0 = ((id & 7) * 8 + (slot & 7)) * TM;
        n0 = (slot >> 3) * TN;
    } else {
        m0 = blockIdx.y * TM;
        n0 = blockIdx.x * TN;
    }

    f32x4 acc[FM][FN] = {};
    stage_tile<TM>(As[0], A + (size_t)m0 * K, K, t);
    stage_tile<TN>(Bs[0], BT + (size_t)n0 * K, K, t);
    __syncthreads();
    int nt = K >> 6;
    int cur = 0;
    for (int kt = 0; kt < nt; ++kt) {
        if (kt + 1 < nt) {
            stage_tile<TM>(As[cur ^ 1], A + (size_t)m0 * K + (kt + 1) * 64, K, t);
            stage_tile<TN>(Bs[cur ^ 1], BT + (size_t)n0 * K + (kt + 1) * 64, K, t);
        }
        #pragma unroll
        for (int kk = 0; kk < 2; ++kk) {
            short8 af[FM], bf[FN];
            #pragma unroll
            for (int f = 0; f < FM; ++f)
                af[f] = rdfrag(As[cur], wr * (TM / 2) + f * 16, kk * 4, lane);
            #pragma unroll
            for (int f = 0; f < FN; ++f)
                bf[f] = rdfrag(Bs[cur], wc * (TN / 2) + f * 16, kk * 4, lane);
            #pragma unroll
            for (int i = 0; i < FM; ++i)
                #pragma unroll
                for (int j = 0; j < FN; ++j)
                    acc[i][j] = mfma16(af[i], bf[j], acc[i][j]);
        }
        __syncthreads();
        cur ^= 1;
    }

    #pragma unroll
    for (int i = 0; i < FM; ++i)
        #pragma unroll
        for (int j = 0; j < FN; ++j)
            #pragma unroll
            for (int r = 0; r < 4; ++r) {
                int m = m0 + wr * (TM / 2) + i * 16 + (lane >> 4) * 4 + r;
                int n = n0 + wc * (TN / 2) + j * 16 + (lane & 15);
                float v = acc[i][j][r] + bias[n];
                if (MODE == 0) {
                    cf[(size_t)m * DIM + n] = v;
                } else if (MODE == 1) {
                    int b = m >> 10, ii = m & 1023;
                    int h = n >> 6, d = n & 63;
                    o1[((size_t)(b * NH + h) * NSINK + ii) * HD + d] = f2bf(v * QSCALE);
                } else {
                    int b = m >> 12, jj = m & 4095;
                    if (n < DIM) {
                        int h = n >> 6, d = n & 63;
                        o1[((size_t)(b * NH + h) * NSRC + jj) * HD + d] = f2bf(v);
                    } else {
                        int nn = n - DIM;
                        int h = nn >> 6, d = nn & 63;
                        o2[((size_t)(b * NH + h) * HD + d) * NSRC + jj] = f2bf(v);
                    }
                }
            }
}

// ---------------- pass A: colsum_part[ic][bh][j] = sum_{i chunk} exp2(q.k) ----------------
// q staged in LDS (shared by 4 waves, dbuf); k frags in regs (loaded once)
__global__ __launch_bounds__(256, 4) void pass_a(const u16* __restrict__ q,
    const u16* __restrict__ k, float* __restrict__ part)
{
    int id = blockIdx.x;
    int slot = id >> 3;
    int bh = (id & 7) + 8 * (slot >> 6);
    int rem = slot & 63;
    int ic = rem >> 4;
    int t = threadIdx.x, wave = t >> 6, lane = t & 63;
    int j0 = (rem & 15) * 256 + wave * 64;
    const u16* qb = q + (size_t)bh * NSINK * HD;
    const u16* kb = k + (size_t)bh * NSRC * HD;

    __shared__ u16 Qs[2][64 * 64];

    short8 kf[4][2];
    #pragma unroll
    for (int jf = 0; jf < 4; ++jf)
        #pragma unroll
        for (int kc = 0; kc < 2; ++kc)
            kf[jf][kc] = ldfrag(kb + (size_t)(j0 + jf * 16) * HD + kc * 32, HD, lane);

    float csum[4] = {};
    stage_tile<64>(Qs[0], qb + (size_t)(ic * 256) * HD, HD, t);
    __syncthreads();
    int cur = 0;
    for (int ii = 0; ii < 4; ++ii) {
        if (ii + 1 < 4)
            stage_tile<64>(Qs[cur ^ 1], qb + (size_t)(ic * 256 + (ii + 1) * 64) * HD, HD, t);
        #pragma unroll
        for (int f = 0; f < 4; ++f) {
            short8 q0 = rdfrag(Qs[cur], f * 16, 0, lane);
            short8 q1 = rdfrag(Qs[cur], f * 16, 4, lane);
            f32x4 s[4] = {};
            #pragma unroll
            for (int jf = 0; jf < 4; ++jf) s[jf] = mfma16(q0, kf[jf][0], s[jf]);
            #pragma unroll
            for (int jf = 0; jf < 4; ++jf) s[jf] = mfma16(q1, kf[jf][1], s[jf]);
            #pragma unroll
            for (int jf = 0; jf < 4; ++jf)
                csum[jf] += fast_exp2(s[jf][0]) + fast_exp2(s[jf][1])
                          + fast_exp2(s[jf][2]) + fast_exp2(s[jf][3]);
        }
        __syncthreads();   // drains prefetch vmcnt; guards buffer reuse
        cur ^= 1;
    }
    #pragma unroll
    for (int jf = 0; jf < 4; ++jf) {
        csum[jf] += __shfl_xor(csum[jf], 16, 64);
        csum[jf] += __shfl_xor(csum[jf], 32, 64);
    }
    if (lane < 16)
        #pragma unroll
        for (int jf = 0; jf < 4; ++jf)
            part[((size_t)ic * BATCH * NH + bh) * NSRC + j0 + jf * 16 + lane] = csum[jf];
}

// ---------------- csred: rcs[bh][j] = 1 / sum_ic part[ic][bh][j] ----------------
__global__ __launch_bounds__(256) void csred(const float* __restrict__ part,
    float* __restrict__ rcs)
{
    int x = blockIdx.x * 256 + threadIdx.x;   // 16*4096 total
    const int S = BATCH * NH * NSRC;
    float cs = part[x] + part[x + S] + part[x + 2 * S] + part[x + 3 * S];
    rcs[x] = fast_rcp(cs);
}

// ---------------- vscale2: vT2 rows = v*rcs (d<64) / rcs (d==64); vsum ----------------
__global__ __launch_bounds__(256) void vscale2(const u16* __restrict__ vTh,
    const float* __restrict__ rcs, float* __restrict__ vs, u16* __restrict__ vT2)
{
    int d = blockIdx.x;   // 0..64
    int bh = blockIdx.y;  // 0..15
    const float* rc = rcs + (size_t)bh * NSRC;
    u16* dst = vT2 + ((size_t)bh * VROWS + d) * NSRC;
    if (d == 64) {
        for (int j = threadIdx.x; j < NSRC; j += 256) dst[j] = f2bf(rc[j]);
        return;
    }
    const u16* src = vTh + ((size_t)bh * HD + d) * NSRC;
    float acc = 0.f;
    for (int j = threadIdx.x; j < NSRC; j += 256) {
        float v = bf2f(src[j]);
        acc += v;
        dst[j] = f2bf(v * rc[j]);
    }
    #pragma unroll
    for (int off = 32; off > 0; off >>= 1) acc += __shfl_down(acc, off, 64);
    __shared__ float r4[4];
    if ((threadIdx.x & 63) == 0) r4[threadIdx.x >> 6] = acc;
    __syncthreads();
    if (threadIdx.x == 0) vs[bh * HD + d] = r4[0] + r4[1] + r4[2] + r4[3];
}

// ---------------- pass B: dbuf; 2 i-frags/wave; P=exp2(KQ^T); in-reg P transpose ----------------
// 1-D grid 512: id%8==bh%8; block covers 128 i (wave: 32), j-quarter loop
__global__ __launch_bounds__(256, 3) void pass_b(const u16* __restrict__ q,
    const u16* __restrict__ k, const u16* __restrict__ vT2,
    u16* __restrict__ pvb, float* __restrict__ rs)
{
    int id = blockIdx.x;
    int slot = id >> 3;              // 0..63
    int bh = (id & 7) + 8 * (slot >> 5);
    int rem = slot & 31;
    int split = rem >> 3;            // 0..3
    int i0 = (rem & 7) * 128;        // 0..896
    int t = threadIdx.x, wave = t >> 6, lane = t & 63;
    const u16* qb = q + (size_t)bh * NSINK * HD;
    const u16* kb = k + (size_t)bh * NSRC * HD;
    const u16* vb = vT2 + (size_t)bh * VROWS * NSRC;

    __shared__ u16 Ks[2][64 * 64];
    __shared__ u16 Vs[2][64 * 64];
    __shared__ alignas(16) u16 Rcs[2][64];
#if !HAVE_PERMLANE
    __shared__ alignas(16) u16 pbuf[4][2][16 * 76];   // fallback transpose buffer
#endif

    short8 qf[2][2];   // [fi][kc]
    #pragma unroll
    for (int fi = 0; fi < 2; ++fi)
        #pragma unroll
        for (int kc = 0; kc < 2; ++kc)
            qf[fi][kc] = ldfrag(qb + (size_t)(i0 + wave * 32 + fi * 16) * HD + kc * 32, HD, lane);

    auto stage = [&](int buf, int jt) {
        int j0 = split * (NSRC / 4) + jt * 64;
        stage_tile<64>(Ks[buf], kb + (size_t)j0 * HD, HD, t);
        stage_tile<64>(Vs[buf], vb + j0, NSRC, t);
        if (t < 8) gld16(vb + (size_t)64 * NSRC + j0 + t * 8, Rcs[buf]);
    };

    f32x4 o[2][5] = {};
    stage(0, 0);
    __syncthreads();
    int cur = 0;
    for (int jt = 0; jt < 16; ++jt) {
        if (jt + 1 < 16) stage(cur ^ 1, jt + 1);   // prefetch overlaps compute
        // swapped QK^T: each K frag read once, feeds both i-frags
        f32x4 s[2][4] = {};
        #pragma unroll
        for (int kc = 0; kc < 2; ++kc)
            #pragma unroll
            for (int jf = 0; jf < 4; ++jf) {
                short8 kf = rdfrag(Ks[cur], jf * 16, kc * 4, lane);
                s[0][jf] = mfma16(kf, qf[0][kc], s[0][jf]);
                s[1][jf] = mfma16(kf, qf[1][kc], s[1][jf]);
            }
        // exp2 in place
        #pragma unroll
        for (int fi = 0; fi < 2; ++fi)
            #pragma unroll
            for (int jf = 0; jf < 4; ++jf)
                #pragma unroll
                for (int r = 0; r < 4; ++r)
                    s[fi][jf][r] = fast_exp2(s[fi][jf][r]);
#if !HAVE_PERMLANE
        #pragma unroll
        for (int fi = 0; fi < 2; ++fi)
            #pragma unroll
            for (int jf = 0; jf < 4; ++jf) {
                uint2 w;
                w.x = pk_bf16(s[fi][jf][0], s[fi][jf][1]);
                w.y = pk_bf16(s[fi][jf][2], s[fi][jf][3]);
                *(uint2*)&pbuf[wave][fi][(size_t)(lane & 15) * 76 + jf * 16 + (lane >> 4) * 4] = w;
            }
#endif
        // PV: each V frag read once, feeds both i-frags; 5th frag = 1/cs (rowsum)
        short8 z = {};
        #pragma unroll
        for (int jc = 0; jc < 2; ++jc) {
#if HAVE_PERMLANE
            short8 pa0 = pa_frag(s[0][2 * jc], s[0][2 * jc + 1]);
            short8 pa1 = pa_frag(s[1][2 * jc], s[1][2 * jc + 1]);
#else
            short8 pa0 = *(const short8*)&pbuf[wave][0][(size_t)(lane & 15) * 76 + jc * 32 + (lane >> 4) * 8];
            short8 pa1 = *(const short8*)&pbuf[wave][1][(size_t)(lane & 15) * 76 + jc * 32 + (lane >> 4) * 8];
#endif
            #pragma unroll
            for (int df = 0; df < 4; ++df) {
                short8 vf = rdfrag(Vs[cur], df * 16, jc * 4, lane);
                o[0][df] = mfma16(pa0, vf, o[0][df]);
                o[1][df] = mfma16(pa1, vf, o[1][df]);
            }
            short8 b5 = z;
            if ((lane & 15) == 0)
                b5 = *(const short8*)&Rcs[cur][jc * 32 + (lane >> 4) * 8];
            o[0][4] = mfma16(pa0, b5, o[0][4]);
            o[1][4] = mfma16(pa1, b5, o[1][4]);
        }
        __syncthreads();   // drains prefetch vmcnt; guards buffer reuse
        cur ^= 1;
    }
    // rowsum = o[fi][4] col 0 (lanes with lane&15==0)
    if ((lane & 15) == 0) {
        #pragma unroll
        for (int fi = 0; fi < 2; ++fi)
            #pragma unroll
            for (int r = 0; r < 4; ++r)
                rs[((size_t)split * (BATCH * NH) + bh) * NSINK + i0 + wave * 32 + fi * 16 + (lane >> 4) * 4 + r] = o[fi][4][r];
    }
    int b = bh >> 3, h = bh & 7;
    u16* pvp = pvb + (size_t)split * BATCH * NSINK * DIM;
    #pragma unroll
    for (int fi = 0; fi < 2; ++fi)
        #pragma unroll
        for (int df = 0; df < 4; ++df)
            #pragma unroll
            for (int r = 0; r < 4; ++r) {
                int row = i0 + wave * 32 + fi * 16 + (lane >> 4) * 4 + r;
                pvp[((size_t)(b * NSINK + row)) * DIM + h * HD + df * 16 + (lane & 15)] = f2bf(o[fi][df][r]);
            }
}

// ---------------- finalize: a = (sum pv + eps*vsum)/(sum rs + Neps) -> bf16 ----------------
__global__ __launch_bounds__(256) void finalize_pv(const u16* __restrict__ pvb,
    const float* __restrict__ rs, const float* __restrict__ vs,
    u16* __restrict__ ab)
{
    const int M = BATCH * NSINK * DIM;
    const int R = BATCH * NH * NSINK;
    int idx = blockIdx.x * 256 + threadIdx.x;
    int m = idx >> 9, n = idx & 511;
    int b = m >> 10, i = m & 1023, h = n >> 6, d = n & 63;
    int bh = b * NH + h;
    float val = bf2f(pvb[idx]) + bf2f(pvb[idx + M]) + bf2f(pvb[idx + 2 * M])
              + bf2f(pvb[idx + 3 * M]) + EPS * vs[bh * HD + d];
    float rsv = rs[bh * NSINK + i] + rs[R + bh * NSINK + i]
              + rs[2 * R + bh * NSINK + i] + rs[3 * R + bh * NSINK + i]
              + (float)NSRC * EPS;
    ab[idx] = f2bf(val / rsv);
}

extern "C" void kernel_launch(void* const* d_in, const int* in_sizes, int n_in,
                              void* d_out, int out_size, void* d_ws, size_t ws_size,
                              hipStream_t stream) {
    (void)in_sizes; (void)n_in; (void)out_size;
    const float* sink    = (const float*)d_in[0];
    const float* source  = (const float*)d_in[1];
    const float* gamma_s = (const float*)d_in[2];
    const float* beta_s  = (const float*)d_in[3];
    const float* gamma_c = (const float*)d_in[4];
    const float* beta_c  = (const float*)d_in[5];
    const float* Wq      = (const float*)d_in[6];
    const float* bq      = (const float*)d_in[7];
    const float* Wkv     = (const float*)d_in[8];
    const float* bkv     = (const float*)d_in[9];
    const float* Wo      = (const float*)d_in[10];
    const float* bo      = (const float*)d_in[11];
    float* out = (float*)d_out;

    char* p = (char*)d_ws;
    auto carve = [&](size_t bytes) { char* r = p; p += (bytes + 255) & ~(size_t)255; return r; };
    u16* sh    = (u16*)carve(2048ull * 512 * 2);       // LN'd sink
    u16* ch    = (u16*)carve(8192ull * 512 * 2);       // LN'd source
    u16* wqT   = (u16*)carve(512ull * 512 * 2);
    u16* wkvT  = (u16*)carve(1024ull * 512 * 2);
    u16* woT   = (u16*)carve(512ull * 512 * 2);
    u16* qb    = (u16*)carve(16ull * 1024 * 64 * 2);
    u16* kb    = (u16*)carve(16ull * 4096 * 64 * 2);
    u16* vTh   = (u16*)carve(16ull * 64 * 4096 * 2);
    u16* vT2   = (u16*)carve(16ull * VROWS * 4096 * 2);
    float* cs_part = (float*)carve(4ull * 16 * 4096 * 4);
    float* rcs     = (float*)carve(16ull * 4096 * 4);
    float* vs      = (float*)carve(1024ull * 4);
    float* rs      = (float*)carve(4ull * 16 * 1024 * 4);
    u16*   pvb     = (u16*)carve(4ull * 2048 * 512 * 2);
    u16*   ab      = (u16*)carve(2048ull * 512 * 2);
    if ((size_t)(p - (char*)d_ws) > ws_size) return;

    prep<<<BATCH * (NSINK + NSRC) + 2048, 256, 0, stream>>>(
        sink, source, gamma_s, beta_s, gamma_c, beta_c,
        Wq, Wkv, Wo, sh, ch, wqT, wkvT, woT);

    gemm1<1, 64, 64, 0><<<dim3(DIM / 64, BATCH * NSINK / 64), 256, 0, stream>>>(
        sh, wqT, bq, 512, nullptr, qb, nullptr);
    // KV: XCD-affine 1-D grid (64 m-tiles x 8 n-tiles)
    gemm1<2, 128, 128, 1><<<512, 256, 0, stream>>>(
        ch, wkvT, bkv, 512, nullptr, kb, vTh);

    pass_a<<<1024, 256, 0, stream>>>(qb, kb, cs_part);
    csred<<<BATCH * NH * NSRC / 256, 256, 0, stream>>>(cs_part, rcs);
    vscale2<<<dim3(VROWS, BATCH * NH), 256, 0, stream>>>(vTh, rcs, vs, vT2);
    pass_b<<<512, 256, 0, stream>>>(qb, kb, vT2, pvb, rs);
    finalize_pv<<<4096, 256, 0, stream>>>(pvb, rs, vs, ab);

    gemm1<0, 64, 64, 0><<<dim3(DIM / 64, BATCH * NSINK / 64), 256, 0, stream>>>(
        ab, woT, bo, 512, out, nullptr, nullptr);
}